// Round 1
// baseline (1105.384 us; speedup 1.0000x reference)
//
#include <hip/hip_runtime.h>

#define NN 50000
#define NE 800000
#define FIN 256
#define C 64
#define NEG_SLOPE 0.01f
#define SCAN_BLOCKS ((NN + 255) / 256)   // 196

__device__ __forceinline__ float leaky(float v) { return v > 0.f ? v : NEG_SLOPE * v; }

// Full-wave (64-lane) sum on the VALU pipe via DPP (no ds_bpermute).
__device__ __forceinline__ float wave_sum(float x) {
    int v = __float_as_int(x);
#define DPP_ADD(ctrl) \
    x += __int_as_float(__builtin_amdgcn_update_dpp(0, v, ctrl, 0xF, 0xF, false)); \
    v = __float_as_int(x);
    DPP_ADD(0x111)  // row_shr:1
    DPP_ADD(0x112)  // row_shr:2
    DPP_ADD(0x114)  // row_shr:4
    DPP_ADD(0x118)  // row_shr:8
    DPP_ADD(0x142)  // row_bcast:15
    DPP_ADD(0x143)  // row_bcast:31
#undef DPP_ADD
    return __int_as_float(__builtin_amdgcn_readlane(v, 63));
}

// ---------------------------------------------------------------------------
// Weight transpose: Wt[m][c][k] = W_m[k][c], m in {q,k,v,skip}. 16384 elems.
// ---------------------------------------------------------------------------
__global__ __launch_bounds__(256) void k_tw(const float* __restrict__ Wq,
                                            const float* __restrict__ Wk,
                                            const float* __restrict__ Wv,
                                            const float* __restrict__ Ws,
                                            float* __restrict__ Wt) {
    const int idx = blockIdx.x * 256 + threadIdx.x;
    if (idx >= 4 * 64 * 64) return;
    const int m = idx >> 12, r = idx & 4095, c = r >> 6, k = r & 63;
    const float* W = (m == 0) ? Wq : (m == 1) ? Wk : (m == 2) ? Wv : Ws;
    Wt[idx] = W[k * 64 + c];
}

// ---------------------------------------------------------------------------
// K0: h = leaky_relu(x @ Wf + bf).  Lane = node; weights streamed uniform.
// Epilogue stages the 64x64-float output tile in T (dead after k-loop) and
// writes coalesced float4 rows (avoids 2x HBM sector amplification).
// ---------------------------------------------------------------------------
__global__ __launch_bounds__(256) void k_feat(const float* __restrict__ x,
                                              const float* __restrict__ Wf,
                                              const float* __restrict__ bf,
                                              float* __restrict__ h) {
    __shared__ float4 T[64][64];  // swizzled, 64 KB
    const int t = threadIdx.x;
    const int base = blockIdx.x * 64;
    const float4* x4 = (const float4*)x;
#pragma unroll
    for (int i = 0; i < 16; ++i) {
        const int idx = t + i * 256;
        const int row = idx >> 6, c4 = idx & 63;
        int n = base + row; if (n >= NN) n = NN - 1;
        T[row][c4 ^ (row & 7)] = x4[(size_t)n * 64 + c4];
    }
    __syncthreads();
    const int lane = t & 63;
    const int q = __builtin_amdgcn_readfirstlane(t) >> 6;
    const float4* Wf4 = (const float4*)Wf;

    float4 acc[4];
#pragma unroll
    for (int cp = 0; cp < 4; ++cp) acc[cp] = make_float4(0.f, 0.f, 0.f, 0.f);

    for (int ch = 0; ch < 64; ++ch) {
        const float4 xv = T[lane][ch ^ (lane & 7)];
#pragma unroll
        for (int j = 0; j < 4; ++j) {
            const float xs_ = (j == 0) ? xv.x : (j == 1) ? xv.y : (j == 2) ? xv.z : xv.w;
            const float4* wr = Wf4 + (size_t)(4 * ch + j) * 16 + q * 4;
#pragma unroll
            for (int cp = 0; cp < 4; ++cp) {
                const float4 w = wr[cp];
                acc[cp].x += xs_ * w.x; acc[cp].y += xs_ * w.y;
                acc[cp].z += xs_ * w.z; acc[cp].w += xs_ * w.w;
            }
        }
    }
    __syncthreads();  // T dead: all waves done with k-loop reads
    {
        const float4* bf4 = (const float4*)bf;
#pragma unroll
        for (int cp = 0; cp < 4; ++cp) {
            const float4 b = bf4[q * 4 + cp];
            float4 r;
            r.x = leaky(acc[cp].x + b.x); r.y = leaky(acc[cp].y + b.y);
            r.z = leaky(acc[cp].z + b.z); r.w = leaky(acc[cp].w + b.w);
            T[lane][(q * 4 + cp) ^ (lane & 7)] = r;   // stage (row=node, col4 0..15)
        }
    }
    __syncthreads();
    // coalesced write-out: each wave writes contiguous float4 runs
#pragma unroll
    for (int i = 0; i < 4; ++i) {
        const int idx = t + i * 256;
        const int row = idx >> 4, c4 = idx & 15;
        const int n = base + row;
        if (n < NN) ((float4*)h)[(size_t)n * 16 + c4] = T[row][c4 ^ (row & 7)];
    }
}

// ---------------------------------------------------------------------------
// K1: qkvs row = [q(64) | k/v interleaved(128) | skip+bias(64)].
// Compute lane=node (uniform scalar weight streams); results staged in LDS
// (reusing the h-tile buffer after fragments are in registers) and written
// out as coalesced float4 rows. Eliminates ~3.7x HBM write amplification.
// ---------------------------------------------------------------------------
__global__ __launch_bounds__(256) void k_qkvs(const float* __restrict__ h,
                                              const float* __restrict__ Wt,
                                              const float* __restrict__ bq,
                                              const float* __restrict__ bk,
                                              const float* __restrict__ bv,
                                              const float* __restrict__ bs,
                                              float* __restrict__ qkvs) {
    __shared__ float4 S[64][64];   // 64 KB: h-tile first (cols 0..15), then out-staging
    const int t = threadIdx.x;
    const int base = blockIdx.x * 64;
    const float4* h4 = (const float4*)h;
#pragma unroll
    for (int i = 0; i < 4; ++i) {
        const int idx = t + i * 256;
        const int row = idx >> 4, c4 = idx & 15;
        int n = base + row; if (n >= NN) n = NN - 1;
        S[row][c4 ^ (row & 7)] = h4[(size_t)n * 16 + c4];
    }
    __syncthreads();
    const int lane = t & 63;
    const int sec = __builtin_amdgcn_readfirstlane(t) >> 6;

    float4 hr[16];
#pragma unroll
    for (int j = 0; j < 16; ++j) hr[j] = S[lane][j ^ (lane & 7)];
    __syncthreads();   // fragments in registers; S reusable as staging

    const float4* Wt4 = (const float4*)Wt;

#define DOT(WROW, OUT) do {                                            \
        float s0 = 0.f, s1 = 0.f, s2 = 0.f, s3 = 0.f;                  \
        _Pragma("unroll")                                              \
        for (int j = 0; j < 16; ++j) {                                 \
            const float4 w = (WROW)[j];                                \
            s0 += hr[j].x * w.x; s1 += hr[j].y * w.y;                  \
            s2 += hr[j].z * w.z; s3 += hr[j].w * w.w;                  \
        }                                                              \
        OUT = (s0 + s1) + (s2 + s3);                                   \
    } while (0)

    if (sec == 0) {               // q -> row floats [0,64) = col4 0..15
        for (int cg = 0; cg < 16; ++cg) {
            float v0, v1, v2, v3;
            DOT(Wt4 + (size_t)(4 * cg + 0) * 16, v0);
            DOT(Wt4 + (size_t)(4 * cg + 1) * 16, v1);
            DOT(Wt4 + (size_t)(4 * cg + 2) * 16, v2);
            DOT(Wt4 + (size_t)(4 * cg + 3) * 16, v3);
            const float4 b = ((const float4*)bq)[cg];
            float4 r;
            r.x = v0 + b.x; r.y = v1 + b.y; r.z = v2 + b.z; r.w = v3 + b.w;
            S[lane][cg ^ (lane & 7)] = r;
        }
    } else if (sec == 1) {        // skip -> row floats [192,256) = col4 48..63
        const float4* Wm = Wt4 + (size_t)3 * 64 * 16;
        for (int cg = 0; cg < 16; ++cg) {
            float v0, v1, v2, v3;
            DOT(Wm + (size_t)(4 * cg + 0) * 16, v0);
            DOT(Wm + (size_t)(4 * cg + 1) * 16, v1);
            DOT(Wm + (size_t)(4 * cg + 2) * 16, v2);
            DOT(Wm + (size_t)(4 * cg + 3) * 16, v3);
            const float4 b = ((const float4*)bs)[cg];
            float4 r;
            r.x = v0 + b.x; r.y = v1 + b.y; r.z = v2 + b.z; r.w = v3 + b.w;
            S[lane][(48 + cg) ^ (lane & 7)] = r;
        }
    } else {                      // kv pairs -> row floats [64,192) = col4 16..47
        const int c0 = (sec - 2) * 32;
        const float4* Wk_ = Wt4 + (size_t)1 * 64 * 16;
        const float4* Wv_ = Wt4 + (size_t)2 * 64 * 16;
        for (int ci = 0; ci < 32; ++ci) {
            const int c = c0 + ci;
            float kc, vc;
            DOT(Wk_ + (size_t)c * 16, kc);
            DOT(Wv_ + (size_t)c * 16, vc);
            float2 r;
            r.x = kc + bk[c];
            r.y = vc + bv[c];
            // float (64+2c) lives in float4 slot 16+(c>>1), half (c&1)
            float2* s2 = (float2*)&S[lane][(16 + (c >> 1)) ^ (lane & 7)];
            s2[c & 1] = r;
        }
    }
#undef DOT
    __syncthreads();
    // coalesced write-out: one contiguous 1KB row segment per wave-instr
#pragma unroll
    for (int i = 0; i < 16; ++i) {
        const int idx = t + i * 256;
        const int row = idx >> 6, c4 = idx & 63;
        const int n = base + row;
        if (n < NN) ((float4*)qkvs)[(size_t)n * 64 + c4] = S[row][c4 ^ (row & 7)];
    }
}

// ---------------------------------------------------------------------------
// CSR build: histogram -> 3-kernel parallel scan -> scatter
// ---------------------------------------------------------------------------
__global__ __launch_bounds__(256) void k_hist(const int* __restrict__ ei,
                                              int* __restrict__ deg) {
    const int e = blockIdx.x * 256 + threadIdx.x;
    if (e >= NE) return;
    atomicAdd(&deg[ei[NE + e]], 1);
}

__global__ __launch_bounds__(256) void k_blocksum(const int* __restrict__ deg,
                                                  int* __restrict__ bsum) {
    __shared__ int sh[256];
    const int t = threadIdx.x;
    const int idx = blockIdx.x * 256 + t;
    sh[t] = (idx < NN) ? deg[idx] : 0;
    __syncthreads();
#pragma unroll
    for (int off = 128; off > 0; off >>= 1) {
        if (t < off) sh[t] += sh[t + off];
        __syncthreads();
    }
    if (t == 0) bsum[blockIdx.x] = sh[0];
}

__global__ __launch_bounds__(256) void k_scanb(const int* __restrict__ bsum,
                                               int* __restrict__ boff) {
    __shared__ int sh[256];
    const int t = threadIdx.x;
    const int v = (t < SCAN_BLOCKS) ? bsum[t] : 0;
    sh[t] = v;
    __syncthreads();
#pragma unroll
    for (int off = 1; off < 256; off <<= 1) {
        const int x = (t >= off) ? sh[t - off] : 0;
        __syncthreads();
        sh[t] += x;
        __syncthreads();
    }
    if (t < SCAN_BLOCKS) boff[t] = sh[t] - v;  // exclusive
}

__global__ __launch_bounds__(256) void k_writeptr(const int* __restrict__ deg,
                                                  const int* __restrict__ boff,
                                                  int* __restrict__ row_ptr,
                                                  int* __restrict__ cursor) {
    __shared__ int sh[256];
    const int t = threadIdx.x;
    const int idx = blockIdx.x * 256 + t;
    const int v = (idx < NN) ? deg[idx] : 0;
    sh[t] = v;
    __syncthreads();
#pragma unroll
    for (int off = 1; off < 256; off <<= 1) {
        const int x = (t >= off) ? sh[t - off] : 0;
        __syncthreads();
        sh[t] += x;
        __syncthreads();
    }
    if (idx < NN) {
        const int r = boff[blockIdx.x] + sh[t] - v;  // exclusive prefix
        row_ptr[idx] = r;
        cursor[idx] = r;
    }
    if (idx == 0) row_ptr[NN] = NE;
}

__global__ __launch_bounds__(256) void k_csr(const int* __restrict__ ei,
                                             const float* __restrict__ eattr,
                                             int* __restrict__ cursor,
                                             float4* __restrict__ erec) {
    const int e = blockIdx.x * 256 + threadIdx.x;
    if (e >= NE) return;
    const int dst = ei[NE + e];
    const int pos = atomicAdd(&cursor[dst], 1);
    erec[pos] = make_float4(__int_as_float(ei[e]), eattr[e * 2], eattr[e * 2 + 1], 0.f);
}

// ---------------------------------------------------------------------------
// K2: fused conv. One wave per destination, flash-style online softmax,
// DPP reduce, float2 k/v gather, 4-edge unroll.
// ---------------------------------------------------------------------------
__global__ __launch_bounds__(256) void k_conv(const int* __restrict__ row_ptr,
                                              const float4* __restrict__ erec,
                                              const float* __restrict__ We,
                                              const float* __restrict__ qkvs,
                                              float* __restrict__ hout) {
    const int lane = threadIdx.x & 63;
    const int wv = __builtin_amdgcn_readfirstlane(threadIdx.x) >> 6;
    const int d = blockIdx.x * 4 + wv;
    if (d >= NN) return;
    const float we0 = We[lane], we1 = We[C + lane];
    const float* qrow = qkvs + (size_t)d * 256;
    const float q = qrow[lane];
    const int i0 = row_ptr[d], i1 = row_ptr[d + 1];

    float m = -INFINITY, l = 0.f, acc = 0.f;
    int i = i0;
    for (; i + 3 < i1; i += 4) {
        const float4 r0 = erec[i], r1 = erec[i + 1], r2 = erec[i + 2], r3 = erec[i + 3];
        const float* b0 = qkvs + (size_t)__float_as_int(r0.x) * 256;
        const float* b1 = qkvs + (size_t)__float_as_int(r1.x) * 256;
        const float* b2 = qkvs + (size_t)__float_as_int(r2.x) * 256;
        const float* b3 = qkvs + (size_t)__float_as_int(r3.x) * 256;
        const float2 kv0 = *(const float2*)(b0 + 64 + 2 * lane);
        const float2 kv1 = *(const float2*)(b1 + 64 + 2 * lane);
        const float2 kv2 = *(const float2*)(b2 + 64 + 2 * lane);
        const float2 kv3 = *(const float2*)(b3 + 64 + 2 * lane);
        const float ec0 = r0.y * we0 + r0.z * we1;
        const float ec1 = r1.y * we0 + r1.z * we1;
        const float ec2 = r2.y * we0 + r2.z * we1;
        const float ec3 = r3.y * we0 + r3.z * we1;
        const float P0 = wave_sum(q * (kv0.x + ec0)) * 0.125f;
        const float P1 = wave_sum(q * (kv1.x + ec1)) * 0.125f;
        const float P2 = wave_sum(q * (kv2.x + ec2)) * 0.125f;
        const float P3 = wave_sum(q * (kv3.x + ec3)) * 0.125f;
        const float mn = fmaxf(fmaxf(m, fmaxf(P0, P1)), fmaxf(P2, P3));
        const float s = __expf(m - mn);
        const float e0 = __expf(P0 - mn), e1 = __expf(P1 - mn);
        const float e2 = __expf(P2 - mn), e3 = __expf(P3 - mn);
        l = l * s + ((e0 + e1) + (e2 + e3));
        acc = acc * s + (kv0.y + ec0) * e0 + (kv1.y + ec1) * e1
                      + (kv2.y + ec2) * e2 + (kv3.y + ec3) * e3;
        m = mn;
    }
    for (; i < i1; ++i) {
        const float4 r0 = erec[i];
        const float* b0 = qkvs + (size_t)__float_as_int(r0.x) * 256;
        const float2 kv0 = *(const float2*)(b0 + 64 + 2 * lane);
        const float ec0 = r0.y * we0 + r0.z * we1;
        const float P0 = wave_sum(q * (kv0.x + ec0)) * 0.125f;
        const float mn = fmaxf(m, P0);
        const float s = __expf(m - mn);
        const float e0 = __expf(P0 - mn);
        l = l * s + e0;
        acc = acc * s + (kv0.y + ec0) * e0;
        m = mn;
    }
    const float res = (l > 0.f) ? acc / l : 0.f;
    hout[(size_t)d * C + lane] = leaky(res + qrow[192 + lane]);
}

extern "C" void kernel_launch(void* const* d_in, const int* in_sizes, int n_in,
                              void* d_out, int out_size, void* d_ws, size_t ws_size,
                              hipStream_t stream) {
    const float* x     = (const float*)d_in[0];
    const int*   ei    = (const int*)d_in[1];
    const float* eattr = (const float*)d_in[2];
    const float* Wf    = (const float*)d_in[3];
    const float* bf    = (const float*)d_in[4];
    const float* Wq    = (const float*)d_in[5];
    const float* bq    = (const float*)d_in[6];
    const float* Wk    = (const float*)d_in[7];
    const float* bk    = (const float*)d_in[8];
    const float* Wv    = (const float*)d_in[9];
    const float* bv    = (const float*)d_in[10];
    const float* We    = (const float*)d_in[11];
    const float* Ws    = (const float*)d_in[12];
    const float* bs    = (const float*)d_in[13];
    float* out = (float*)d_out;

    // workspace layout
    char* p = (char*)d_ws;
    float*  h       = (float*)p;  p += (size_t)NN * C * 4;        // 12.8 MB
    float*  qkvs    = (float*)p;  p += (size_t)NN * 4 * C * 4;    // 51.2 MB
    float*  Wt      = (float*)p;  p += (size_t)4 * 64 * 64 * 4;   // 64 KB
    int*    deg     = (int*)p;    p += (size_t)NN * 4;
    int*    row_ptr = (int*)p;    p += (size_t)(NN + 1) * 4;
    int*    cursor  = (int*)p;    p += (size_t)NN * 4;
    int*    bsum    = (int*)p;    p += (size_t)SCAN_BLOCKS * 4;
    int*    boff    = (int*)p;    p += (size_t)SCAN_BLOCKS * 4;
    float4* erec    = (float4*)p; p += (size_t)NE * 16;           // 12.8 MB

    // One-time per call: weight transpose + CSR build
    k_tw<<<64, 256, 0, stream>>>(Wq, Wk, Wv, Ws, Wt);
    hipMemsetAsync(deg, 0, (size_t)NN * 4, stream);
    k_hist<<<(NE + 255) / 256, 256, 0, stream>>>(ei, deg);
    k_blocksum<<<SCAN_BLOCKS, 256, 0, stream>>>(deg, bsum);
    k_scanb<<<1, 256, 0, stream>>>(bsum, boff);
    k_writeptr<<<SCAN_BLOCKS, 256, 0, stream>>>(deg, boff, row_ptr, cursor);
    k_csr<<<(NE + 255) / 256, 256, 0, stream>>>(ei, eattr, cursor, erec);

    const int gemm_grid = (NN + 63) / 64;   // 782
    k_feat<<<gemm_grid, 256, 0, stream>>>(x, Wf, bf, h);

    for (int layer = 0; layer < 3; ++layer) {
        k_qkvs<<<gemm_grid, 256, 0, stream>>>(h, Wt, bq, bk, bv, bs, qkvs);
        float* hout = (layer == 2) ? out : h;
        k_conv<<<(NN + 3) / 4, 256, 0, stream>>>(row_ptr, erec, We, qkvs, hout);
    }
}

// Round 2
// 555.018 us; speedup vs baseline: 1.9916x; 1.9916x over previous
//
#include <hip/hip_runtime.h>

#define NN 50000
#define NE 800000
#define FIN 256
#define C 64
#define NEG_SLOPE 0.01f
#define SCAN_BLOCKS ((NN + 255) / 256)   // 196

typedef float f32x16 __attribute__((ext_vector_type(16)));

__device__ __forceinline__ float leaky(float v) { return v > 0.f ? v : NEG_SLOPE * v; }

// Full-wave (64-lane) sum on the VALU pipe via DPP (no ds_bpermute).
__device__ __forceinline__ float wave_sum(float x) {
    int v = __float_as_int(x);
#define DPP_ADD(ctrl) \
    x += __int_as_float(__builtin_amdgcn_update_dpp(0, v, ctrl, 0xF, 0xF, false)); \
    v = __float_as_int(x);
    DPP_ADD(0x111)  // row_shr:1
    DPP_ADD(0x112)  // row_shr:2
    DPP_ADD(0x114)  // row_shr:4
    DPP_ADD(0x118)  // row_shr:8
    DPP_ADD(0x142)  // row_bcast:15
    DPP_ADD(0x143)  // row_bcast:31
#undef DPP_ADD
    return __int_as_float(__builtin_amdgcn_readlane(v, 63));
}

// ---------------------------------------------------------------------------
// Weight transpose: Wt[m][c][k] = W_m[k][c], m in {q,k,v,skip}. 16384 elems.
// ---------------------------------------------------------------------------
__global__ __launch_bounds__(256) void k_tw(const float* __restrict__ Wq,
                                            const float* __restrict__ Wk,
                                            const float* __restrict__ Wv,
                                            const float* __restrict__ Ws,
                                            float* __restrict__ Wt) {
    const int idx = blockIdx.x * 256 + threadIdx.x;
    if (idx >= 4 * 64 * 64) return;
    const int m = idx >> 12, r = idx & 4095, c = r >> 6, k = r & 63;
    const float* W = (m == 0) ? Wq : (m == 1) ? Wk : (m == 2) ? Wv : Ws;
    Wt[idx] = W[k * 64 + c];
}

// ---------------------------------------------------------------------------
// K0: h = leaky_relu(x @ Wf + bf).  Lane = node; weights streamed uniform.
// Epilogue stages the 64x64-float output tile in T (dead after k-loop) and
// writes coalesced float4 rows.
// ---------------------------------------------------------------------------
__global__ __launch_bounds__(256) void k_feat(const float* __restrict__ x,
                                              const float* __restrict__ Wf,
                                              const float* __restrict__ bf,
                                              float* __restrict__ h) {
    __shared__ float4 T[64][64];  // swizzled, 64 KB
    const int t = threadIdx.x;
    const int base = blockIdx.x * 64;
    const float4* x4 = (const float4*)x;
#pragma unroll
    for (int i = 0; i < 16; ++i) {
        const int idx = t + i * 256;
        const int row = idx >> 6, c4 = idx & 63;
        int n = base + row; if (n >= NN) n = NN - 1;
        T[row][c4 ^ (row & 7)] = x4[(size_t)n * 64 + c4];
    }
    __syncthreads();
    const int lane = t & 63;
    const int q = __builtin_amdgcn_readfirstlane(t) >> 6;
    const float4* Wf4 = (const float4*)Wf;

    float4 acc[4];
#pragma unroll
    for (int cp = 0; cp < 4; ++cp) acc[cp] = make_float4(0.f, 0.f, 0.f, 0.f);

    for (int ch = 0; ch < 64; ++ch) {
        const float4 xv = T[lane][ch ^ (lane & 7)];
#pragma unroll
        for (int j = 0; j < 4; ++j) {
            const float xs_ = (j == 0) ? xv.x : (j == 1) ? xv.y : (j == 2) ? xv.z : xv.w;
            const float4* wr = Wf4 + (size_t)(4 * ch + j) * 16 + q * 4;
#pragma unroll
            for (int cp = 0; cp < 4; ++cp) {
                const float4 w = wr[cp];
                acc[cp].x += xs_ * w.x; acc[cp].y += xs_ * w.y;
                acc[cp].z += xs_ * w.z; acc[cp].w += xs_ * w.w;
            }
        }
    }
    __syncthreads();  // T dead: all waves done with k-loop reads
    {
        const float4* bf4 = (const float4*)bf;
#pragma unroll
        for (int cp = 0; cp < 4; ++cp) {
            const float4 b = bf4[q * 4 + cp];
            float4 r;
            r.x = leaky(acc[cp].x + b.x); r.y = leaky(acc[cp].y + b.y);
            r.z = leaky(acc[cp].z + b.z); r.w = leaky(acc[cp].w + b.w);
            T[lane][(q * 4 + cp) ^ (lane & 7)] = r;   // stage (row=node, col4 0..15)
        }
    }
    __syncthreads();
    // coalesced write-out: each wave writes contiguous float4 runs
#pragma unroll
    for (int i = 0; i < 4; ++i) {
        const int idx = t + i * 256;
        const int row = idx >> 4, c4 = idx & 15;
        const int n = base + row;
        if (n < NN) ((float4*)h)[(size_t)n * 16 + c4] = T[row][c4 ^ (row & 7)];
    }
}

// ---------------------------------------------------------------------------
// K1: qkvs row = [q(64) | k/v interleaved(128) | skip+bias(64)].
// Transposed thread mapping: lane = output column, loop over nodes.
// Per-lane weight column (16 float4 VGPRs); h row broadcast via SGPRs
// (s_load_dwordx16 x4, wave-uniform address). Store is 64x4B = 256B
// contiguous per node per wave — fully coalesced, zero LDS.
// ---------------------------------------------------------------------------
#define QKVS_NPB 32   // nodes per block

__global__ __launch_bounds__(256) void k_qkvs(const float* __restrict__ h,
                                              const float* __restrict__ Wt,
                                              const float* __restrict__ bq,
                                              const float* __restrict__ bk,
                                              const float* __restrict__ bv,
                                              const float* __restrict__ bs,
                                              float* __restrict__ qkvs) {
    const int t = threadIdx.x;
    const int lane = t & 63;
    const int sec = __builtin_amdgcn_readfirstlane(t) >> 6;
    const int base = blockIdx.x * QKVS_NPB;

    // section -> (matrix m, weight column c, output float offset, bias)
    int m, cidx, off;
    float bias;
    if (sec == 0)      { m = 0; cidx = lane; off = 0;   bias = bq[lane]; }
    else if (sec == 1) { m = 3; cidx = lane; off = 192; bias = bs[lane]; }
    else {
        cidx = ((sec - 2) << 5) + (lane >> 1);   // k/v column
        m = 1 + (lane & 1);                      // even lane -> Wk (1), odd -> Wv (2)
        off = (sec == 2) ? 64 : 128;
        bias = (lane & 1) ? bv[cidx] : bk[cidx];
    }

    // preload this lane's weight column: Wt[m][cidx][k], k = 0..63
    const float4* wb = (const float4*)(Wt + ((size_t)m << 12) + ((size_t)cidx << 6));
    float4 w[16];
#pragma unroll
    for (int j = 0; j < 16; ++j) w[j] = wb[j];

    const int nmax = (base + QKVS_NPB <= NN) ? QKVS_NPB : (NN - base);
    for (int i = 0; i < nmax; ++i) {
        const float* hrow = h + (size_t)(base + i) * 64;   // wave-uniform
        f32x16 ha, hb, hc, hd;
        asm volatile("s_load_dwordx16 %0, %4, 0x0\n\t"
                     "s_load_dwordx16 %1, %4, 0x40\n\t"
                     "s_load_dwordx16 %2, %4, 0x80\n\t"
                     "s_load_dwordx16 %3, %4, 0xc0\n\t"
                     "s_waitcnt lgkmcnt(0)"
                     : "=&s"(ha), "=&s"(hb), "=&s"(hc), "=&s"(hd)
                     : "s"(hrow));
        float a0 = 0.f, a1 = 0.f, a2 = 0.f, a3 = 0.f;
#pragma unroll
        for (int j = 0; j < 4; ++j) {
            a0 = fmaf(ha[4 * j + 0], w[j].x, a0);
            a1 = fmaf(ha[4 * j + 1], w[j].y, a1);
            a2 = fmaf(ha[4 * j + 2], w[j].z, a2);
            a3 = fmaf(ha[4 * j + 3], w[j].w, a3);
        }
#pragma unroll
        for (int j = 0; j < 4; ++j) {
            a0 = fmaf(hb[4 * j + 0], w[4 + j].x, a0);
            a1 = fmaf(hb[4 * j + 1], w[4 + j].y, a1);
            a2 = fmaf(hb[4 * j + 2], w[4 + j].z, a2);
            a3 = fmaf(hb[4 * j + 3], w[4 + j].w, a3);
        }
#pragma unroll
        for (int j = 0; j < 4; ++j) {
            a0 = fmaf(hc[4 * j + 0], w[8 + j].x, a0);
            a1 = fmaf(hc[4 * j + 1], w[8 + j].y, a1);
            a2 = fmaf(hc[4 * j + 2], w[8 + j].z, a2);
            a3 = fmaf(hc[4 * j + 3], w[8 + j].w, a3);
        }
#pragma unroll
        for (int j = 0; j < 4; ++j) {
            a0 = fmaf(hd[4 * j + 0], w[12 + j].x, a0);
            a1 = fmaf(hd[4 * j + 1], w[12 + j].y, a1);
            a2 = fmaf(hd[4 * j + 2], w[12 + j].z, a2);
            a3 = fmaf(hd[4 * j + 3], w[12 + j].w, a3);
        }
        qkvs[(size_t)(base + i) * 256 + off + lane] = ((a0 + a1) + (a2 + a3)) + bias;
    }
}

// ---------------------------------------------------------------------------
// CSR build: histogram -> 3-kernel parallel scan -> scatter
// ---------------------------------------------------------------------------
__global__ __launch_bounds__(256) void k_hist(const int* __restrict__ ei,
                                              int* __restrict__ deg) {
    const int e = blockIdx.x * 256 + threadIdx.x;
    if (e >= NE) return;
    atomicAdd(&deg[ei[NE + e]], 1);
}

__global__ __launch_bounds__(256) void k_blocksum(const int* __restrict__ deg,
                                                  int* __restrict__ bsum) {
    __shared__ int sh[256];
    const int t = threadIdx.x;
    const int idx = blockIdx.x * 256 + t;
    sh[t] = (idx < NN) ? deg[idx] : 0;
    __syncthreads();
#pragma unroll
    for (int off = 128; off > 0; off >>= 1) {
        if (t < off) sh[t] += sh[t + off];
        __syncthreads();
    }
    if (t == 0) bsum[blockIdx.x] = sh[0];
}

__global__ __launch_bounds__(256) void k_scanb(const int* __restrict__ bsum,
                                               int* __restrict__ boff) {
    __shared__ int sh[256];
    const int t = threadIdx.x;
    const int v = (t < SCAN_BLOCKS) ? bsum[t] : 0;
    sh[t] = v;
    __syncthreads();
#pragma unroll
    for (int off = 1; off < 256; off <<= 1) {
        const int x = (t >= off) ? sh[t - off] : 0;
        __syncthreads();
        sh[t] += x;
        __syncthreads();
    }
    if (t < SCAN_BLOCKS) boff[t] = sh[t] - v;  // exclusive
}

__global__ __launch_bounds__(256) void k_writeptr(const int* __restrict__ deg,
                                                  const int* __restrict__ boff,
                                                  int* __restrict__ row_ptr,
                                                  int* __restrict__ cursor) {
    __shared__ int sh[256];
    const int t = threadIdx.x;
    const int idx = blockIdx.x * 256 + t;
    const int v = (idx < NN) ? deg[idx] : 0;
    sh[t] = v;
    __syncthreads();
#pragma unroll
    for (int off = 1; off < 256; off <<= 1) {
        const int x = (t >= off) ? sh[t - off] : 0;
        __syncthreads();
        sh[t] += x;
        __syncthreads();
    }
    if (idx < NN) {
        const int r = boff[blockIdx.x] + sh[t] - v;  // exclusive prefix
        row_ptr[idx] = r;
        cursor[idx] = r;
    }
    if (idx == 0) row_ptr[NN] = NE;
}

__global__ __launch_bounds__(256) void k_csr(const int* __restrict__ ei,
                                             const float* __restrict__ eattr,
                                             int* __restrict__ cursor,
                                             float4* __restrict__ erec) {
    const int e = blockIdx.x * 256 + threadIdx.x;
    if (e >= NE) return;
    const int dst = ei[NE + e];
    const int pos = atomicAdd(&cursor[dst], 1);
    erec[pos] = make_float4(__int_as_float(ei[e]), eattr[e * 2], eattr[e * 2 + 1], 0.f);
}

// ---------------------------------------------------------------------------
// K2: fused conv. One wave per destination, flash-style online softmax,
// DPP reduce, float2 k/v gather, 4-edge unroll.
// ---------------------------------------------------------------------------
__global__ __launch_bounds__(256) void k_conv(const int* __restrict__ row_ptr,
                                              const float4* __restrict__ erec,
                                              const float* __restrict__ We,
                                              const float* __restrict__ qkvs,
                                              float* __restrict__ hout) {
    const int lane = threadIdx.x & 63;
    const int wv = __builtin_amdgcn_readfirstlane(threadIdx.x) >> 6;
    const int d = blockIdx.x * 4 + wv;
    if (d >= NN) return;
    const float we0 = We[lane], we1 = We[C + lane];
    const float* qrow = qkvs + (size_t)d * 256;
    const float q = qrow[lane];
    const int i0 = row_ptr[d], i1 = row_ptr[d + 1];

    float m = -INFINITY, l = 0.f, acc = 0.f;
    int i = i0;
    for (; i + 3 < i1; i += 4) {
        const float4 r0 = erec[i], r1 = erec[i + 1], r2 = erec[i + 2], r3 = erec[i + 3];
        const float* b0 = qkvs + (size_t)__float_as_int(r0.x) * 256;
        const float* b1 = qkvs + (size_t)__float_as_int(r1.x) * 256;
        const float* b2 = qkvs + (size_t)__float_as_int(r2.x) * 256;
        const float* b3 = qkvs + (size_t)__float_as_int(r3.x) * 256;
        const float2 kv0 = *(const float2*)(b0 + 64 + 2 * lane);
        const float2 kv1 = *(const float2*)(b1 + 64 + 2 * lane);
        const float2 kv2 = *(const float2*)(b2 + 64 + 2 * lane);
        const float2 kv3 = *(const float2*)(b3 + 64 + 2 * lane);
        const float ec0 = r0.y * we0 + r0.z * we1;
        const float ec1 = r1.y * we0 + r1.z * we1;
        const float ec2 = r2.y * we0 + r2.z * we1;
        const float ec3 = r3.y * we0 + r3.z * we1;
        const float P0 = wave_sum(q * (kv0.x + ec0)) * 0.125f;
        const float P1 = wave_sum(q * (kv1.x + ec1)) * 0.125f;
        const float P2 = wave_sum(q * (kv2.x + ec2)) * 0.125f;
        const float P3 = wave_sum(q * (kv3.x + ec3)) * 0.125f;
        const float mn = fmaxf(fmaxf(m, fmaxf(P0, P1)), fmaxf(P2, P3));
        const float s = __expf(m - mn);
        const float e0 = __expf(P0 - mn), e1 = __expf(P1 - mn);
        const float e2 = __expf(P2 - mn), e3 = __expf(P3 - mn);
        l = l * s + ((e0 + e1) + (e2 + e3));
        acc = acc * s + (kv0.y + ec0) * e0 + (kv1.y + ec1) * e1
                      + (kv2.y + ec2) * e2 + (kv3.y + ec3) * e3;
        m = mn;
    }
    for (; i < i1; ++i) {
        const float4 r0 = erec[i];
        const float* b0 = qkvs + (size_t)__float_as_int(r0.x) * 256;
        const float2 kv0 = *(const float2*)(b0 + 64 + 2 * lane);
        const float ec0 = r0.y * we0 + r0.z * we1;
        const float P0 = wave_sum(q * (kv0.x + ec0)) * 0.125f;
        const float mn = fmaxf(m, P0);
        const float s = __expf(m - mn);
        const float e0 = __expf(P0 - mn);
        l = l * s + e0;
        acc = acc * s + (kv0.y + ec0) * e0;
        m = mn;
    }
    const float res = (l > 0.f) ? acc / l : 0.f;
    hout[(size_t)d * C + lane] = leaky(res + qrow[192 + lane]);
}

extern "C" void kernel_launch(void* const* d_in, const int* in_sizes, int n_in,
                              void* d_out, int out_size, void* d_ws, size_t ws_size,
                              hipStream_t stream) {
    const float* x     = (const float*)d_in[0];
    const int*   ei    = (const int*)d_in[1];
    const float* eattr = (const float*)d_in[2];
    const float* Wf    = (const float*)d_in[3];
    const float* bf    = (const float*)d_in[4];
    const float* Wq    = (const float*)d_in[5];
    const float* bq    = (const float*)d_in[6];
    const float* Wk    = (const float*)d_in[7];
    const float* bk    = (const float*)d_in[8];
    const float* Wv    = (const float*)d_in[9];
    const float* bv    = (const float*)d_in[10];
    const float* We    = (const float*)d_in[11];
    const float* Ws    = (const float*)d_in[12];
    const float* bs    = (const float*)d_in[13];
    float* out = (float*)d_out;

    // workspace layout
    char* p = (char*)d_ws;
    float*  h       = (float*)p;  p += (size_t)NN * C * 4;        // 12.8 MB
    float*  qkvs    = (float*)p;  p += (size_t)NN * 4 * C * 4;    // 51.2 MB
    float*  Wt      = (float*)p;  p += (size_t)4 * 64 * 64 * 4;   // 64 KB
    int*    deg     = (int*)p;    p += (size_t)NN * 4;
    int*    row_ptr = (int*)p;    p += (size_t)(NN + 1) * 4;
    int*    cursor  = (int*)p;    p += (size_t)NN * 4;
    int*    bsum    = (int*)p;    p += (size_t)SCAN_BLOCKS * 4;
    int*    boff    = (int*)p;    p += (size_t)SCAN_BLOCKS * 4;
    float4* erec    = (float4*)p; p += (size_t)NE * 16;           // 12.8 MB

    // One-time per call: weight transpose + CSR build
    k_tw<<<64, 256, 0, stream>>>(Wq, Wk, Wv, Ws, Wt);
    hipMemsetAsync(deg, 0, (size_t)NN * 4, stream);
    k_hist<<<(NE + 255) / 256, 256, 0, stream>>>(ei, deg);
    k_blocksum<<<SCAN_BLOCKS, 256, 0, stream>>>(deg, bsum);
    k_scanb<<<1, 256, 0, stream>>>(bsum, boff);
    k_writeptr<<<SCAN_BLOCKS, 256, 0, stream>>>(deg, boff, row_ptr, cursor);
    k_csr<<<(NE + 255) / 256, 256, 0, stream>>>(ei, eattr, cursor, erec);

    const int gemm_grid = (NN + 63) / 64;       // 782 (k_feat)
    const int qkvs_grid = (NN + QKVS_NPB - 1) / QKVS_NPB;  // 1563

    k_feat<<<gemm_grid, 256, 0, stream>>>(x, Wf, bf, h);

    for (int layer = 0; layer < 3; ++layer) {
        k_qkvs<<<qkvs_grid, 256, 0, stream>>>(h, Wt, bq, bk, bv, bs, qkvs);
        float* hout = (layer == 2) ? out : h;
        k_conv<<<(NN + 3) / 4, 256, 0, stream>>>(row_ptr, erec, We, qkvs, hout);
    }
}

// Round 3
// 539.477 us; speedup vs baseline: 2.0490x; 1.0288x over previous
//
#include <hip/hip_runtime.h>
#include <hip/hip_fp16.h>

#define NN 50000
#define NE 800000
#define FIN 256
#define C 64
#define NEG_SLOPE 0.01f
#define SCAN_BLOCKS ((NN + 255) / 256)   // 196

typedef float f32x16 __attribute__((ext_vector_type(16)));

__device__ __forceinline__ float leaky(float v) { return v > 0.f ? v : NEG_SLOPE * v; }

// Full-wave (64-lane) sum on the VALU pipe via DPP (no ds_bpermute).
__device__ __forceinline__ float wave_sum(float x) {
    int v = __float_as_int(x);
#define DPP_ADD(ctrl) \
    x += __int_as_float(__builtin_amdgcn_update_dpp(0, v, ctrl, 0xF, 0xF, false)); \
    v = __float_as_int(x);
    DPP_ADD(0x111)  // row_shr:1
    DPP_ADD(0x112)  // row_shr:2
    DPP_ADD(0x114)  // row_shr:4
    DPP_ADD(0x118)  // row_shr:8
    DPP_ADD(0x142)  // row_bcast:15
    DPP_ADD(0x143)  // row_bcast:31
#undef DPP_ADD
    return __int_as_float(__builtin_amdgcn_readlane(v, 63));
}

// ---------------------------------------------------------------------------
// Weight transposes:
//   Wt[m][c][k]  = W_m[k][c], m in {q,k,v,skip} (16384 elems)
//   Wft[c][k]    = Wf[k][c], c in [0,64), k in [0,256) (16384 elems)
// ---------------------------------------------------------------------------
__global__ __launch_bounds__(256) void k_tw(const float* __restrict__ Wq,
                                            const float* __restrict__ Wk,
                                            const float* __restrict__ Wv,
                                            const float* __restrict__ Ws,
                                            const float* __restrict__ Wf,
                                            float* __restrict__ Wt,
                                            float* __restrict__ Wft) {
    const int idx = blockIdx.x * 256 + threadIdx.x;
    if (idx < 4 * 64 * 64) {
        const int m = idx >> 12, r = idx & 4095, c = r >> 6, k = r & 63;
        const float* W = (m == 0) ? Wq : (m == 1) ? Wk : (m == 2) ? Wv : Ws;
        Wt[idx] = W[k * 64 + c];
    } else if (idx < 2 * 4 * 64 * 64) {
        const int j = idx - 4 * 64 * 64;
        const int c = j >> 8, k = j & 255;
        Wft[j] = Wf[k * 64 + c];
    }
}

// ---------------------------------------------------------------------------
// K0: h = leaky_relu(x @ Wf + bf).  Transposed mapping (k_qkvs pattern):
// lane = output column, wave = k-quarter (64 of 256). Per-lane weight slice
// in 16 float4 VGPRs; x-row quarter broadcast via s_load_dwordx16. Partials
// combined across the 4 waves through a 32KB LDS buffer, one sync, then
// fully-coalesced stores.
// ---------------------------------------------------------------------------
#define FEAT_NPB 32   // nodes per block

__global__ __launch_bounds__(256) void k_feat(const float* __restrict__ x,
                                              const float* __restrict__ Wft,
                                              const float* __restrict__ bf,
                                              float* __restrict__ h) {
    __shared__ float part[FEAT_NPB][4][64];   // 32 KB
    const int t = threadIdx.x;
    const int lane = t & 63;
    const int w = __builtin_amdgcn_readfirstlane(t) >> 6;   // k-quarter
    const int base = blockIdx.x * FEAT_NPB;

    // lane's weight slice: Wft[lane][64w .. 64w+63]
    const float4* wb = (const float4*)(Wft + (size_t)lane * 256 + w * 64);
    float4 wr[16];
#pragma unroll
    for (int j = 0; j < 16; ++j) wr[j] = wb[j];

    const int nmax = (base + FEAT_NPB <= NN) ? FEAT_NPB : (NN - base);
    for (int i = 0; i < nmax; ++i) {
        const float* xrow = x + (size_t)(base + i) * 256 + w * 64;  // wave-uniform
        f32x16 ha, hb, hc, hd;
        asm volatile("s_load_dwordx16 %0, %4, 0x0\n\t"
                     "s_load_dwordx16 %1, %4, 0x40\n\t"
                     "s_load_dwordx16 %2, %4, 0x80\n\t"
                     "s_load_dwordx16 %3, %4, 0xc0\n\t"
                     "s_waitcnt lgkmcnt(0)"
                     : "=&s"(ha), "=&s"(hb), "=&s"(hc), "=&s"(hd)
                     : "s"(xrow));
        float a0 = 0.f, a1 = 0.f, a2 = 0.f, a3 = 0.f;
#pragma unroll
        for (int j = 0; j < 4; ++j) {
            a0 = fmaf(ha[4 * j + 0], wr[j].x, a0);
            a1 = fmaf(ha[4 * j + 1], wr[j].y, a1);
            a2 = fmaf(ha[4 * j + 2], wr[j].z, a2);
            a3 = fmaf(ha[4 * j + 3], wr[j].w, a3);
        }
#pragma unroll
        for (int j = 0; j < 4; ++j) {
            a0 = fmaf(hb[4 * j + 0], wr[4 + j].x, a0);
            a1 = fmaf(hb[4 * j + 1], wr[4 + j].y, a1);
            a2 = fmaf(hb[4 * j + 2], wr[4 + j].z, a2);
            a3 = fmaf(hb[4 * j + 3], wr[4 + j].w, a3);
        }
#pragma unroll
        for (int j = 0; j < 4; ++j) {
            a0 = fmaf(hc[4 * j + 0], wr[8 + j].x, a0);
            a1 = fmaf(hc[4 * j + 1], wr[8 + j].y, a1);
            a2 = fmaf(hc[4 * j + 2], wr[8 + j].z, a2);
            a3 = fmaf(hc[4 * j + 3], wr[8 + j].w, a3);
        }
#pragma unroll
        for (int j = 0; j < 4; ++j) {
            a0 = fmaf(hd[4 * j + 0], wr[12 + j].x, a0);
            a1 = fmaf(hd[4 * j + 1], wr[12 + j].y, a1);
            a2 = fmaf(hd[4 * j + 2], wr[12 + j].z, a2);
            a3 = fmaf(hd[4 * j + 3], wr[12 + j].w, a3);
        }
        part[i][w][lane] = (a0 + a1) + (a2 + a3);
    }
    __syncthreads();
#pragma unroll
    for (int j = 0; j < 8; ++j) {
        const int o = t + j * 256;
        const int node = o >> 6, col = o & 63;
        const int n = base + node;
        if (n < NN) {
            const float r = part[node][0][col] + part[node][1][col]
                          + part[node][2][col] + part[node][3][col] + bf[col];
            h[(size_t)n * 64 + col] = leaky(r);
        }
    }
}

// ---------------------------------------------------------------------------
// K1: qkvs row (192 floats = 768B): [q f32(64) | k/v fp16 interleaved(128h) |
// skip f32(64)].  Transposed mapping, SGPR h-row broadcast, coalesced stores.
// ---------------------------------------------------------------------------
#define QKVS_NPB 32   // nodes per block

__global__ __launch_bounds__(256) void k_qkvs(const float* __restrict__ h,
                                              const float* __restrict__ Wt,
                                              const float* __restrict__ bq,
                                              const float* __restrict__ bk,
                                              const float* __restrict__ bv,
                                              const float* __restrict__ bs,
                                              float* __restrict__ qkvs) {
    const int t = threadIdx.x;
    const int lane = t & 63;
    const int sec = __builtin_amdgcn_readfirstlane(t) >> 6;
    const int base = blockIdx.x * QKVS_NPB;

    // section -> (matrix m, weight column c, bias)
    int m, cidx;
    float bias;
    if (sec == 0)      { m = 0; cidx = lane; bias = bq[lane]; }
    else if (sec == 1) { m = 3; cidx = lane; bias = bs[lane]; }
    else {
        cidx = ((sec - 2) << 5) + (lane >> 1);   // k/v column
        m = 1 + (lane & 1);                      // even lane -> Wk, odd -> Wv
        bias = (lane & 1) ? bv[cidx] : bk[cidx];
    }

    // preload this lane's weight column: Wt[m][cidx][k], k = 0..63
    const float4* wb = (const float4*)(Wt + ((size_t)m << 12) + ((size_t)cidx << 6));
    float4 w[16];
#pragma unroll
    for (int j = 0; j < 16; ++j) w[j] = wb[j];

    const int nmax = (base + QKVS_NPB <= NN) ? QKVS_NPB : (NN - base);
    for (int i = 0; i < nmax; ++i) {
        const float* hrow = h + (size_t)(base + i) * 64;   // wave-uniform
        f32x16 ha, hb, hc, hd;
        asm volatile("s_load_dwordx16 %0, %4, 0x0\n\t"
                     "s_load_dwordx16 %1, %4, 0x40\n\t"
                     "s_load_dwordx16 %2, %4, 0x80\n\t"
                     "s_load_dwordx16 %3, %4, 0xc0\n\t"
                     "s_waitcnt lgkmcnt(0)"
                     : "=&s"(ha), "=&s"(hb), "=&s"(hc), "=&s"(hd)
                     : "s"(hrow));
        float a0 = 0.f, a1 = 0.f, a2 = 0.f, a3 = 0.f;
#pragma unroll
        for (int j = 0; j < 4; ++j) {
            a0 = fmaf(ha[4 * j + 0], w[j].x, a0);
            a1 = fmaf(ha[4 * j + 1], w[j].y, a1);
            a2 = fmaf(ha[4 * j + 2], w[j].z, a2);
            a3 = fmaf(ha[4 * j + 3], w[j].w, a3);
        }
#pragma unroll
        for (int j = 0; j < 4; ++j) {
            a0 = fmaf(hb[4 * j + 0], w[4 + j].x, a0);
            a1 = fmaf(hb[4 * j + 1], w[4 + j].y, a1);
            a2 = fmaf(hb[4 * j + 2], w[4 + j].z, a2);
            a3 = fmaf(hb[4 * j + 3], w[4 + j].w, a3);
        }
#pragma unroll
        for (int j = 0; j < 4; ++j) {
            a0 = fmaf(hc[4 * j + 0], w[8 + j].x, a0);
            a1 = fmaf(hc[4 * j + 1], w[8 + j].y, a1);
            a2 = fmaf(hc[4 * j + 2], w[8 + j].z, a2);
            a3 = fmaf(hc[4 * j + 3], w[8 + j].w, a3);
        }
#pragma unroll
        for (int j = 0; j < 4; ++j) {
            a0 = fmaf(hd[4 * j + 0], w[12 + j].x, a0);
            a1 = fmaf(hd[4 * j + 1], w[12 + j].y, a1);
            a2 = fmaf(hd[4 * j + 2], w[12 + j].z, a2);
            a3 = fmaf(hd[4 * j + 3], w[12 + j].w, a3);
        }
        const float val = ((a0 + a1) + (a2 + a3)) + bias;
        float* orow = qkvs + (size_t)(base + i) * 192;
        if (sec == 0) {
            orow[lane] = val;                              // q, f32
        } else if (sec == 1) {
            orow[128 + lane] = val;                        // skip, f32
        } else {
            // kv fp16: half index = (sec==2 ? 0 : 64) + lane, contiguous 128B
            __half* kvh = (__half*)(orow + 64);
            kvh[((sec - 2) << 6) + lane] = __float2half(val);
        }
    }
}

// ---------------------------------------------------------------------------
// CSR build: histogram -> 3-kernel parallel scan -> scatter
// ---------------------------------------------------------------------------
__global__ __launch_bounds__(256) void k_hist(const int* __restrict__ ei,
                                              int* __restrict__ deg) {
    const int e = blockIdx.x * 256 + threadIdx.x;
    if (e >= NE) return;
    atomicAdd(&deg[ei[NE + e]], 1);
}

__global__ __launch_bounds__(256) void k_blocksum(const int* __restrict__ deg,
                                                  int* __restrict__ bsum) {
    __shared__ int sh[256];
    const int t = threadIdx.x;
    const int idx = blockIdx.x * 256 + t;
    sh[t] = (idx < NN) ? deg[idx] : 0;
    __syncthreads();
#pragma unroll
    for (int off = 128; off > 0; off >>= 1) {
        if (t < off) sh[t] += sh[t + off];
        __syncthreads();
    }
    if (t == 0) bsum[blockIdx.x] = sh[0];
}

__global__ __launch_bounds__(256) void k_scanb(const int* __restrict__ bsum,
                                               int* __restrict__ boff) {
    __shared__ int sh[256];
    const int t = threadIdx.x;
    const int v = (t < SCAN_BLOCKS) ? bsum[t] : 0;
    sh[t] = v;
    __syncthreads();
#pragma unroll
    for (int off = 1; off < 256; off <<= 1) {
        const int x = (t >= off) ? sh[t - off] : 0;
        __syncthreads();
        sh[t] += x;
        __syncthreads();
    }
    if (t < SCAN_BLOCKS) boff[t] = sh[t] - v;  // exclusive
}

__global__ __launch_bounds__(256) void k_writeptr(const int* __restrict__ deg,
                                                  const int* __restrict__ boff,
                                                  int* __restrict__ row_ptr,
                                                  int* __restrict__ cursor) {
    __shared__ int sh[256];
    const int t = threadIdx.x;
    const int idx = blockIdx.x * 256 + t;
    const int v = (idx < NN) ? deg[idx] : 0;
    sh[t] = v;
    __syncthreads();
#pragma unroll
    for (int off = 1; off < 256; off <<= 1) {
        const int x = (t >= off) ? sh[t - off] : 0;
        __syncthreads();
        sh[t] += x;
        __syncthreads();
    }
    if (idx < NN) {
        const int r = boff[blockIdx.x] + sh[t] - v;  // exclusive prefix
        row_ptr[idx] = r;
        cursor[idx] = r;
    }
    if (idx == 0) row_ptr[NN] = NE;
}

__global__ __launch_bounds__(256) void k_csr(const int* __restrict__ ei,
                                             const float* __restrict__ eattr,
                                             int* __restrict__ cursor,
                                             float4* __restrict__ erec) {
    const int e = blockIdx.x * 256 + threadIdx.x;
    if (e >= NE) return;
    const int dst = ei[NE + e];
    const int pos = atomicAdd(&cursor[dst], 1);
    erec[pos] = make_float4(__int_as_float(ei[e]), eattr[e * 2], eattr[e * 2 + 1], 0.f);
}

// ---------------------------------------------------------------------------
// K2: fused conv. One wave per destination, flash-style online softmax.
// fp16 k/v gather (dword per lane); edge-feature algebra hoisted:
//   alpha = (q.k + a0*(q.We0) + a1*(q.We1)) / 8
//   out   = (sum a*v + S1*We0 + S2*We1) / l,  S1 = sum a*a0, S2 = sum a*a1
// ---------------------------------------------------------------------------
__global__ __launch_bounds__(256) void k_conv(const int* __restrict__ row_ptr,
                                              const float4* __restrict__ erec,
                                              const float* __restrict__ We,
                                              const float* __restrict__ qkvs,
                                              float* __restrict__ hout) {
    const int lane = threadIdx.x & 63;
    const int wv = __builtin_amdgcn_readfirstlane(threadIdx.x) >> 6;
    const int d = blockIdx.x * 4 + wv;
    if (d >= NN) return;
    const float we0 = We[lane], we1 = We[C + lane];
    const float* qrow = qkvs + (size_t)d * 192;
    const float q = qrow[lane];
    const float g0 = wave_sum(q * we0);
    const float g1 = wave_sum(q * we1);
    const int i0 = row_ptr[d], i1 = row_ptr[d + 1];

    float m = -INFINITY, l = 0.f, acc = 0.f, S1 = 0.f, S2 = 0.f;
    int i = i0;
    for (; i + 3 < i1; i += 4) {
        const float4 r0 = erec[i], r1 = erec[i + 1], r2 = erec[i + 2], r3 = erec[i + 3];
        const __half2* b0 = (const __half2*)(qkvs + (size_t)__float_as_int(r0.x) * 192 + 64);
        const __half2* b1 = (const __half2*)(qkvs + (size_t)__float_as_int(r1.x) * 192 + 64);
        const __half2* b2 = (const __half2*)(qkvs + (size_t)__float_as_int(r2.x) * 192 + 64);
        const __half2* b3 = (const __half2*)(qkvs + (size_t)__float_as_int(r3.x) * 192 + 64);
        const __half2 kv0 = b0[lane], kv1 = b1[lane], kv2 = b2[lane], kv3 = b3[lane];
        const float kf0 = __low2float(kv0), vf0 = __high2float(kv0);
        const float kf1 = __low2float(kv1), vf1 = __high2float(kv1);
        const float kf2 = __low2float(kv2), vf2 = __high2float(kv2);
        const float kf3 = __low2float(kv3), vf3 = __high2float(kv3);
        const float P0 = (wave_sum(q * kf0) + g0 * r0.y + g1 * r0.z) * 0.125f;
        const float P1 = (wave_sum(q * kf1) + g0 * r1.y + g1 * r1.z) * 0.125f;
        const float P2 = (wave_sum(q * kf2) + g0 * r2.y + g1 * r2.z) * 0.125f;
        const float P3 = (wave_sum(q * kf3) + g0 * r3.y + g1 * r3.z) * 0.125f;
        const float mn = fmaxf(fmaxf(m, fmaxf(P0, P1)), fmaxf(P2, P3));
        const float s = __expf(m - mn);
        const float e0 = __expf(P0 - mn), e1 = __expf(P1 - mn);
        const float e2 = __expf(P2 - mn), e3 = __expf(P3 - mn);
        l = l * s + ((e0 + e1) + (e2 + e3));
        acc = acc * s + vf0 * e0 + vf1 * e1 + vf2 * e2 + vf3 * e3;
        S1 = S1 * s + r0.y * e0 + r1.y * e1 + r2.y * e2 + r3.y * e3;
        S2 = S2 * s + r0.z * e0 + r1.z * e1 + r2.z * e2 + r3.z * e3;
        m = mn;
    }
    for (; i < i1; ++i) {
        const float4 r0 = erec[i];
        const __half2* b0 = (const __half2*)(qkvs + (size_t)__float_as_int(r0.x) * 192 + 64);
        const __half2 kv0 = b0[lane];
        const float kf0 = __low2float(kv0), vf0 = __high2float(kv0);
        const float P0 = (wave_sum(q * kf0) + g0 * r0.y + g1 * r0.z) * 0.125f;
        const float mn = fmaxf(m, P0);
        const float s = __expf(m - mn);
        const float e0 = __expf(P0 - mn);
        l = l * s + e0;
        acc = acc * s + vf0 * e0;
        S1 = S1 * s + r0.y * e0;
        S2 = S2 * s + r0.z * e0;
        m = mn;
    }
    const float res = (l > 0.f) ? (acc + S1 * we0 + S2 * we1) / l : 0.f;
    hout[(size_t)d * C + lane] = leaky(res + qrow[128 + lane]);
}

extern "C" void kernel_launch(void* const* d_in, const int* in_sizes, int n_in,
                              void* d_out, int out_size, void* d_ws, size_t ws_size,
                              hipStream_t stream) {
    const float* x     = (const float*)d_in[0];
    const int*   ei    = (const int*)d_in[1];
    const float* eattr = (const float*)d_in[2];
    const float* Wf    = (const float*)d_in[3];
    const float* bf    = (const float*)d_in[4];
    const float* Wq    = (const float*)d_in[5];
    const float* bq    = (const float*)d_in[6];
    const float* Wk    = (const float*)d_in[7];
    const float* bk    = (const float*)d_in[8];
    const float* Wv    = (const float*)d_in[9];
    const float* bv    = (const float*)d_in[10];
    const float* We    = (const float*)d_in[11];
    const float* Ws    = (const float*)d_in[12];
    const float* bs    = (const float*)d_in[13];
    float* out = (float*)d_out;

    // workspace layout
    char* p = (char*)d_ws;
    float*  h       = (float*)p;  p += (size_t)NN * C * 4;        // 12.8 MB
    float*  qkvs    = (float*)p;  p += (size_t)NN * 192 * 4;      // 38.4 MB
    float*  Wt      = (float*)p;  p += (size_t)4 * 64 * 64 * 4;   // 64 KB
    float*  Wft     = (float*)p;  p += (size_t)4 * 64 * 64 * 4;   // 64 KB
    int*    deg     = (int*)p;    p += (size_t)NN * 4;
    int*    row_ptr = (int*)p;    p += (size_t)(NN + 1) * 4;
    int*    cursor  = (int*)p;    p += (size_t)NN * 4;
    int*    bsum    = (int*)p;    p += (size_t)SCAN_BLOCKS * 4;
    int*    boff    = (int*)p;    p += (size_t)SCAN_BLOCKS * 4;
    float4* erec    = (float4*)p; p += (size_t)NE * 16;           // 12.8 MB

    // One-time per call: weight transposes + CSR build
    k_tw<<<128, 256, 0, stream>>>(Wq, Wk, Wv, Ws, Wf, Wt, Wft);
    hipMemsetAsync(deg, 0, (size_t)NN * 4, stream);
    k_hist<<<(NE + 255) / 256, 256, 0, stream>>>(ei, deg);
    k_blocksum<<<SCAN_BLOCKS, 256, 0, stream>>>(deg, bsum);
    k_scanb<<<1, 256, 0, stream>>>(bsum, boff);
    k_writeptr<<<SCAN_BLOCKS, 256, 0, stream>>>(deg, boff, row_ptr, cursor);
    k_csr<<<(NE + 255) / 256, 256, 0, stream>>>(ei, eattr, cursor, erec);

    const int feat_grid = (NN + FEAT_NPB - 1) / FEAT_NPB;   // 1563
    const int qkvs_grid = (NN + QKVS_NPB - 1) / QKVS_NPB;   // 1563

    k_feat<<<feat_grid, 256, 0, stream>>>(x, Wft, bf, h);

    for (int layer = 0; layer < 3; ++layer) {
        k_qkvs<<<qkvs_grid, 256, 0, stream>>>(h, Wt, bq, bk, bv, bs, qkvs);
        float* hout = (layer == 2) ? out : h;
        k_conv<<<(NN + 3) / 4, 256, 0, stream>>>(row_ptr, erec, We, qkvs, hout);
    }
}

// Round 4
// 499.132 us; speedup vs baseline: 2.2146x; 1.0808x over previous
//
#include <hip/hip_runtime.h>
#include <hip/hip_fp16.h>

#define NN 50000
#define NE 800000
#define FIN 256
#define C 64
#define NEG_SLOPE 0.01f
#define SCAN_BLOCKS ((NN + 255) / 256)   // 196

typedef float f32x16 __attribute__((ext_vector_type(16)));

__device__ __forceinline__ float leaky(float v) { return v > 0.f ? v : NEG_SLOPE * v; }

// Full-wave (64-lane) sum on the VALU pipe via DPP (no ds_bpermute).
__device__ __forceinline__ float wave_sum(float x) {
    int v = __float_as_int(x);
#define DPP_ADD(ctrl) \
    x += __int_as_float(__builtin_amdgcn_update_dpp(0, v, ctrl, 0xF, 0xF, false)); \
    v = __float_as_int(x);
    DPP_ADD(0x111)  // row_shr:1
    DPP_ADD(0x112)  // row_shr:2
    DPP_ADD(0x114)  // row_shr:4
    DPP_ADD(0x118)  // row_shr:8
    DPP_ADD(0x142)  // row_bcast:15
    DPP_ADD(0x143)  // row_bcast:31
#undef DPP_ADD
    return __int_as_float(__builtin_amdgcn_readlane(v, 63));
}

// ---------------------------------------------------------------------------
// Weight transpose: Wt[m][c][k] = W_m[k][c], m in {q,k,v,skip}. 16384 elems.
// ---------------------------------------------------------------------------
__global__ __launch_bounds__(256) void k_tw(const float* __restrict__ Wq,
                                            const float* __restrict__ Wk,
                                            const float* __restrict__ Wv,
                                            const float* __restrict__ Ws,
                                            float* __restrict__ Wt) {
    const int idx = blockIdx.x * 256 + threadIdx.x;
    if (idx >= 4 * 64 * 64) return;
    const int m = idx >> 12, r = idx & 4095, c = r >> 6, k = r & 63;
    const float* W = (m == 0) ? Wq : (m == 1) ? Wk : (m == 2) ? Wv : Ws;
    Wt[idx] = W[k * 64 + c];
}

// ---------------------------------------------------------------------------
// K0: h = leaky_relu(x @ Wf + bf).
// x is COLD (51.2 MB, read once) -> stage via the VECTOR path into LDS
// (coalesced float4), broadcast to lanes with wave-uniform ds_read_b128
// (same-address = free broadcast). lane = output column, wave = k-quarter,
// weights per-lane straight from Wf (coalesced, L2-hot, 64 VGPRs).
// Cross-wave reduction through a 16KB partials buffer. 32KB LDS total.
// 50000 = 16 * 3125 exactly -> no bounds checks.
// ---------------------------------------------------------------------------
#define FEAT_NPB 16   // nodes per block

__global__ __launch_bounds__(256) void k_feat(const float* __restrict__ x,
                                              const float* __restrict__ Wf,
                                              const float* __restrict__ bf,
                                              float* __restrict__ h) {
    __shared__ float4 Sx[FEAT_NPB][64];       // 16 KB x-tile [node][col4]
    __shared__ float part[FEAT_NPB][4][64];   // 16 KB partial sums
    const int t = threadIdx.x;
    const int lane = t & 63;
    const int w = __builtin_amdgcn_readfirstlane(t) >> 6;   // k-quarter
    const int base = blockIdx.x * FEAT_NPB;

    // stage x-tile: vector path, fully coalesced (1KB per wave-instr)
    const float4* x4 = (const float4*)x;
#pragma unroll
    for (int i = 0; i < 4; ++i) {
        const int idx = t + i * 256;
        const int row = idx >> 6, c4 = idx & 63;
        Sx[row][c4] = x4[(size_t)(base + row) * 64 + c4];
    }

    // per-lane weights: wrk[k'] = Wf[(64w+k')][lane], coalesced 256B loads
    float wrk[64];
#pragma unroll
    for (int k = 0; k < 64; ++k)
        wrk[k] = Wf[(size_t)(w * 64 + k) * 64 + lane];

    __syncthreads();

#pragma unroll
    for (int i = 0; i < FEAT_NPB; ++i) {
        float a0 = 0.f, a1 = 0.f, a2 = 0.f, a3 = 0.f;
#pragma unroll
        for (int j = 0; j < 16; ++j) {
            const float4 xv = Sx[i][w * 16 + j];   // wave-uniform -> broadcast
            a0 = fmaf(xv.x, wrk[4 * j + 0], a0);
            a1 = fmaf(xv.y, wrk[4 * j + 1], a1);
            a2 = fmaf(xv.z, wrk[4 * j + 2], a2);
            a3 = fmaf(xv.w, wrk[4 * j + 3], a3);
        }
        part[i][w][lane] = (a0 + a1) + (a2 + a3);
    }
    __syncthreads();

#pragma unroll
    for (int j = 0; j < 4; ++j) {
        const int o = t + j * 256;
        const int node = o >> 6, col = o & 63;
        const float r = part[node][0][col] + part[node][1][col]
                      + part[node][2][col] + part[node][3][col] + bf[col];
        h[(size_t)(base + node) * 64 + col] = leaky(r);
    }
}

// ---------------------------------------------------------------------------
// K1: qkvs row (192 floats = 768B): [q f32(64) | k/v fp16 interleaved(128h) |
// skip f32(64)].  Transposed mapping, SGPR h-row broadcast (h is L2-hot ->
// short s_load latency), coalesced stores.
// ---------------------------------------------------------------------------
#define QKVS_NPB 32   // nodes per block

__global__ __launch_bounds__(256) void k_qkvs(const float* __restrict__ h,
                                              const float* __restrict__ Wt,
                                              const float* __restrict__ bq,
                                              const float* __restrict__ bk,
                                              const float* __restrict__ bv,
                                              const float* __restrict__ bs,
                                              float* __restrict__ qkvs) {
    const int t = threadIdx.x;
    const int lane = t & 63;
    const int sec = __builtin_amdgcn_readfirstlane(t) >> 6;
    const int base = blockIdx.x * QKVS_NPB;

    // section -> (matrix m, weight column c, bias)
    int m, cidx;
    float bias;
    if (sec == 0)      { m = 0; cidx = lane; bias = bq[lane]; }
    else if (sec == 1) { m = 3; cidx = lane; bias = bs[lane]; }
    else {
        cidx = ((sec - 2) << 5) + (lane >> 1);   // k/v column
        m = 1 + (lane & 1);                      // even lane -> Wk, odd -> Wv
        bias = (lane & 1) ? bv[cidx] : bk[cidx];
    }

    // preload this lane's weight column: Wt[m][cidx][k], k = 0..63
    const float4* wb = (const float4*)(Wt + ((size_t)m << 12) + ((size_t)cidx << 6));
    float4 w[16];
#pragma unroll
    for (int j = 0; j < 16; ++j) w[j] = wb[j];

    const int nmax = (base + QKVS_NPB <= NN) ? QKVS_NPB : (NN - base);
    for (int i = 0; i < nmax; ++i) {
        const float* hrow = h + (size_t)(base + i) * 64;   // wave-uniform
        f32x16 ha, hb, hc, hd;
        asm volatile("s_load_dwordx16 %0, %4, 0x0\n\t"
                     "s_load_dwordx16 %1, %4, 0x40\n\t"
                     "s_load_dwordx16 %2, %4, 0x80\n\t"
                     "s_load_dwordx16 %3, %4, 0xc0\n\t"
                     "s_waitcnt lgkmcnt(0)"
                     : "=&s"(ha), "=&s"(hb), "=&s"(hc), "=&s"(hd)
                     : "s"(hrow));
        float a0 = 0.f, a1 = 0.f, a2 = 0.f, a3 = 0.f;
#pragma unroll
        for (int j = 0; j < 4; ++j) {
            a0 = fmaf(ha[4 * j + 0], w[j].x, a0);
            a1 = fmaf(ha[4 * j + 1], w[j].y, a1);
            a2 = fmaf(ha[4 * j + 2], w[j].z, a2);
            a3 = fmaf(ha[4 * j + 3], w[j].w, a3);
        }
#pragma unroll
        for (int j = 0; j < 4; ++j) {
            a0 = fmaf(hb[4 * j + 0], w[4 + j].x, a0);
            a1 = fmaf(hb[4 * j + 1], w[4 + j].y, a1);
            a2 = fmaf(hb[4 * j + 2], w[4 + j].z, a2);
            a3 = fmaf(hb[4 * j + 3], w[4 + j].w, a3);
        }
#pragma unroll
        for (int j = 0; j < 4; ++j) {
            a0 = fmaf(hc[4 * j + 0], w[8 + j].x, a0);
            a1 = fmaf(hc[4 * j + 1], w[8 + j].y, a1);
            a2 = fmaf(hc[4 * j + 2], w[8 + j].z, a2);
            a3 = fmaf(hc[4 * j + 3], w[8 + j].w, a3);
        }
#pragma unroll
        for (int j = 0; j < 4; ++j) {
            a0 = fmaf(hd[4 * j + 0], w[12 + j].x, a0);
            a1 = fmaf(hd[4 * j + 1], w[12 + j].y, a1);
            a2 = fmaf(hd[4 * j + 2], w[12 + j].z, a2);
            a3 = fmaf(hd[4 * j + 3], w[12 + j].w, a3);
        }
        const float val = ((a0 + a1) + (a2 + a3)) + bias;
        float* orow = qkvs + (size_t)(base + i) * 192;
        if (sec == 0) {
            orow[lane] = val;                              // q, f32
        } else if (sec == 1) {
            orow[128 + lane] = val;                        // skip, f32
        } else {
            // kv fp16: half index = (sec==2 ? 0 : 64) + lane, contiguous 128B
            __half* kvh = (__half*)(orow + 64);
            kvh[((sec - 2) << 6) + lane] = __float2half(val);
        }
    }
}

// ---------------------------------------------------------------------------
// CSR build: histogram -> 3-kernel parallel scan -> scatter
// ---------------------------------------------------------------------------
__global__ __launch_bounds__(256) void k_hist(const int* __restrict__ ei,
                                              int* __restrict__ deg) {
    const int e = blockIdx.x * 256 + threadIdx.x;
    if (e >= NE) return;
    atomicAdd(&deg[ei[NE + e]], 1);
}

__global__ __launch_bounds__(256) void k_blocksum(const int* __restrict__ deg,
                                                  int* __restrict__ bsum) {
    __shared__ int sh[256];
    const int t = threadIdx.x;
    const int idx = blockIdx.x * 256 + t;
    sh[t] = (idx < NN) ? deg[idx] : 0;
    __syncthreads();
#pragma unroll
    for (int off = 128; off > 0; off >>= 1) {
        if (t < off) sh[t] += sh[t + off];
        __syncthreads();
    }
    if (t == 0) bsum[blockIdx.x] = sh[0];
}

__global__ __launch_bounds__(256) void k_scanb(const int* __restrict__ bsum,
                                               int* __restrict__ boff) {
    __shared__ int sh[256];
    const int t = threadIdx.x;
    const int v = (t < SCAN_BLOCKS) ? bsum[t] : 0;
    sh[t] = v;
    __syncthreads();
#pragma unroll
    for (int off = 1; off < 256; off <<= 1) {
        const int x = (t >= off) ? sh[t - off] : 0;
        __syncthreads();
        sh[t] += x;
        __syncthreads();
    }
    if (t < SCAN_BLOCKS) boff[t] = sh[t] - v;  // exclusive
}

__global__ __launch_bounds__(256) void k_writeptr(const int* __restrict__ deg,
                                                  const int* __restrict__ boff,
                                                  int* __restrict__ row_ptr,
                                                  int* __restrict__ cursor) {
    __shared__ int sh[256];
    const int t = threadIdx.x;
    const int idx = blockIdx.x * 256 + t;
    const int v = (idx < NN) ? deg[idx] : 0;
    sh[t] = v;
    __syncthreads();
#pragma unroll
    for (int off = 1; off < 256; off <<= 1) {
        const int x = (t >= off) ? sh[t - off] : 0;
        __syncthreads();
        sh[t] += x;
        __syncthreads();
    }
    if (idx < NN) {
        const int r = boff[blockIdx.x] + sh[t] - v;  // exclusive prefix
        row_ptr[idx] = r;
        cursor[idx] = r;
    }
    if (idx == 0) row_ptr[NN] = NE;
}

__global__ __launch_bounds__(256) void k_csr(const int* __restrict__ ei,
                                             const float* __restrict__ eattr,
                                             int* __restrict__ cursor,
                                             float4* __restrict__ erec) {
    const int e = blockIdx.x * 256 + threadIdx.x;
    if (e >= NE) return;
    const int dst = ei[NE + e];
    const int pos = atomicAdd(&cursor[dst], 1);
    erec[pos] = make_float4(__int_as_float(ei[e]), eattr[e * 2], eattr[e * 2 + 1], 0.f);
}

// ---------------------------------------------------------------------------
// K2: fused conv. One wave per destination, flash-style online softmax.
// fp16 k/v gather (dword per lane); edge-feature algebra hoisted:
//   alpha = (q.k + a0*(q.We0) + a1*(q.We1)) / 8
//   out   = (sum a*v + S1*We0 + S2*We1) / l,  S1 = sum a*a0, S2 = sum a*a1
// ---------------------------------------------------------------------------
__global__ __launch_bounds__(256) void k_conv(const int* __restrict__ row_ptr,
                                              const float4* __restrict__ erec,
                                              const float* __restrict__ We,
                                              const float* __restrict__ qkvs,
                                              float* __restrict__ hout) {
    const int lane = threadIdx.x & 63;
    const int wv = __builtin_amdgcn_readfirstlane(threadIdx.x) >> 6;
    const int d = blockIdx.x * 4 + wv;
    if (d >= NN) return;
    const float we0 = We[lane], we1 = We[C + lane];
    const float* qrow = qkvs + (size_t)d * 192;
    const float q = qrow[lane];
    const float g0 = wave_sum(q * we0);
    const float g1 = wave_sum(q * we1);
    const int i0 = row_ptr[d], i1 = row_ptr[d + 1];

    float m = -INFINITY, l = 0.f, acc = 0.f, S1 = 0.f, S2 = 0.f;
    int i = i0;
    for (; i + 3 < i1; i += 4) {
        const float4 r0 = erec[i], r1 = erec[i + 1], r2 = erec[i + 2], r3 = erec[i + 3];
        const __half2* b0 = (const __half2*)(qkvs + (size_t)__float_as_int(r0.x) * 192 + 64);
        const __half2* b1 = (const __half2*)(qkvs + (size_t)__float_as_int(r1.x) * 192 + 64);
        const __half2* b2 = (const __half2*)(qkvs + (size_t)__float_as_int(r2.x) * 192 + 64);
        const __half2* b3 = (const __half2*)(qkvs + (size_t)__float_as_int(r3.x) * 192 + 64);
        const __half2 kv0 = b0[lane], kv1 = b1[lane], kv2 = b2[lane], kv3 = b3[lane];
        const float kf0 = __low2float(kv0), vf0 = __high2float(kv0);
        const float kf1 = __low2float(kv1), vf1 = __high2float(kv1);
        const float kf2 = __low2float(kv2), vf2 = __high2float(kv2);
        const float kf3 = __low2float(kv3), vf3 = __high2float(kv3);
        const float P0 = (wave_sum(q * kf0) + g0 * r0.y + g1 * r0.z) * 0.125f;
        const float P1 = (wave_sum(q * kf1) + g0 * r1.y + g1 * r1.z) * 0.125f;
        const float P2 = (wave_sum(q * kf2) + g0 * r2.y + g1 * r2.z) * 0.125f;
        const float P3 = (wave_sum(q * kf3) + g0 * r3.y + g1 * r3.z) * 0.125f;
        const float mn = fmaxf(fmaxf(m, fmaxf(P0, P1)), fmaxf(P2, P3));
        const float s = __expf(m - mn);
        const float e0 = __expf(P0 - mn), e1 = __expf(P1 - mn);
        const float e2 = __expf(P2 - mn), e3 = __expf(P3 - mn);
        l = l * s + ((e0 + e1) + (e2 + e3));
        acc = acc * s + vf0 * e0 + vf1 * e1 + vf2 * e2 + vf3 * e3;
        S1 = S1 * s + r0.y * e0 + r1.y * e1 + r2.y * e2 + r3.y * e3;
        S2 = S2 * s + r0.z * e0 + r1.z * e1 + r2.z * e2 + r3.z * e3;
        m = mn;
    }
    for (; i < i1; ++i) {
        const float4 r0 = erec[i];
        const __half2* b0 = (const __half2*)(qkvs + (size_t)__float_as_int(r0.x) * 192 + 64);
        const __half2 kv0 = b0[lane];
        const float kf0 = __low2float(kv0), vf0 = __high2float(kv0);
        const float P0 = (wave_sum(q * kf0) + g0 * r0.y + g1 * r0.z) * 0.125f;
        const float mn = fmaxf(m, P0);
        const float s = __expf(m - mn);
        const float e0 = __expf(P0 - mn);
        l = l * s + e0;
        acc = acc * s + vf0 * e0;
        S1 = S1 * s + r0.y * e0;
        S2 = S2 * s + r0.z * e0;
        m = mn;
    }
    const float res = (l > 0.f) ? (acc + S1 * we0 + S2 * we1) / l : 0.f;
    hout[(size_t)d * C + lane] = leaky(res + qrow[128 + lane]);
}

extern "C" void kernel_launch(void* const* d_in, const int* in_sizes, int n_in,
                              void* d_out, int out_size, void* d_ws, size_t ws_size,
                              hipStream_t stream) {
    const float* x     = (const float*)d_in[0];
    const int*   ei    = (const int*)d_in[1];
    const float* eattr = (const float*)d_in[2];
    const float* Wf    = (const float*)d_in[3];
    const float* bf    = (const float*)d_in[4];
    const float* Wq    = (const float*)d_in[5];
    const float* bq    = (const float*)d_in[6];
    const float* Wk    = (const float*)d_in[7];
    const float* bk    = (const float*)d_in[8];
    const float* Wv    = (const float*)d_in[9];
    const float* bv    = (const float*)d_in[10];
    const float* We    = (const float*)d_in[11];
    const float* Ws    = (const float*)d_in[12];
    const float* bs    = (const float*)d_in[13];
    float* out = (float*)d_out;

    // workspace layout
    char* p = (char*)d_ws;
    float*  h       = (float*)p;  p += (size_t)NN * C * 4;        // 12.8 MB
    float*  qkvs    = (float*)p;  p += (size_t)NN * 192 * 4;      // 38.4 MB
    float*  Wt      = (float*)p;  p += (size_t)4 * 64 * 64 * 4;   // 64 KB
    int*    deg     = (int*)p;    p += (size_t)NN * 4;
    int*    row_ptr = (int*)p;    p += (size_t)(NN + 1) * 4;
    int*    cursor  = (int*)p;    p += (size_t)NN * 4;
    int*    bsum    = (int*)p;    p += (size_t)SCAN_BLOCKS * 4;
    int*    boff    = (int*)p;    p += (size_t)SCAN_BLOCKS * 4;
    float4* erec    = (float4*)p; p += (size_t)NE * 16;           // 12.8 MB

    // One-time per call: weight transpose + CSR build
    k_tw<<<64, 256, 0, stream>>>(Wq, Wk, Wv, Ws, Wt);
    hipMemsetAsync(deg, 0, (size_t)NN * 4, stream);
    k_hist<<<(NE + 255) / 256, 256, 0, stream>>>(ei, deg);
    k_blocksum<<<SCAN_BLOCKS, 256, 0, stream>>>(deg, bsum);
    k_scanb<<<1, 256, 0, stream>>>(bsum, boff);
    k_writeptr<<<SCAN_BLOCKS, 256, 0, stream>>>(deg, boff, row_ptr, cursor);
    k_csr<<<(NE + 255) / 256, 256, 0, stream>>>(ei, eattr, cursor, erec);

    const int feat_grid = NN / FEAT_NPB;                    // 3125 exact
    const int qkvs_grid = (NN + QKVS_NPB - 1) / QKVS_NPB;   // 1563

    k_feat<<<feat_grid, 256, 0, stream>>>(x, Wf, bf, h);

    for (int layer = 0; layer < 3; ++layer) {
        k_qkvs<<<qkvs_grid, 256, 0, stream>>>(h, Wt, bq, bk, bv, bs, qkvs);
        float* hout = (layer == 2) ? out : h;
        k_conv<<<(NN + 3) / 4, 256, 0, stream>>>(row_ptr, erec, We, qkvs, hout);
    }
}

// Round 5
// 497.170 us; speedup vs baseline: 2.2234x; 1.0039x over previous
//
#include <hip/hip_runtime.h>
#include <hip/hip_fp16.h>

#define NN 50000
#define NE 800000
#define FIN 256
#define C 64
#define NEG_SLOPE 0.01f
#define SCAN_BLOCKS ((NN + 255) / 256)   // 196

typedef float f32x16 __attribute__((ext_vector_type(16)));

__device__ __forceinline__ float leaky(float v) { return v > 0.f ? v : NEG_SLOPE * v; }

// ---------------------------------------------------------------------------
// Weight transpose: Wt[m][c][k] = W_m[k][c], m in {q,k,v,skip}. 16384 elems.
// ---------------------------------------------------------------------------
__global__ __launch_bounds__(256) void k_tw(const float* __restrict__ Wq,
                                            const float* __restrict__ Wk,
                                            const float* __restrict__ Wv,
                                            const float* __restrict__ Ws,
                                            float* __restrict__ Wt) {
    const int idx = blockIdx.x * 256 + threadIdx.x;
    if (idx >= 4 * 64 * 64) return;
    const int m = idx >> 12, r = idx & 4095, c = r >> 6, k = r & 63;
    const float* W = (m == 0) ? Wq : (m == 1) ? Wk : (m == 2) ? Wv : Ws;
    Wt[idx] = W[k * 64 + c];
}

// ---------------------------------------------------------------------------
// K0: h = leaky_relu(x @ Wf + bf).
// x is COLD (51.2 MB, read once) -> stage via the VECTOR path into LDS
// (coalesced float4), broadcast to lanes with wave-uniform ds_read_b128.
// lane = output column, wave = k-quarter, weights per-lane from Wf.
// ---------------------------------------------------------------------------
#define FEAT_NPB 16   // nodes per block

__global__ __launch_bounds__(256) void k_feat(const float* __restrict__ x,
                                              const float* __restrict__ Wf,
                                              const float* __restrict__ bf,
                                              float* __restrict__ h) {
    __shared__ float4 Sx[FEAT_NPB][64];       // 16 KB x-tile [node][col4]
    __shared__ float part[FEAT_NPB][4][64];   // 16 KB partial sums
    const int t = threadIdx.x;
    const int lane = t & 63;
    const int w = __builtin_amdgcn_readfirstlane(t) >> 6;   // k-quarter
    const int base = blockIdx.x * FEAT_NPB;

    const float4* x4 = (const float4*)x;
#pragma unroll
    for (int i = 0; i < 4; ++i) {
        const int idx = t + i * 256;
        const int row = idx >> 6, c4 = idx & 63;
        Sx[row][c4] = x4[(size_t)(base + row) * 64 + c4];
    }

    float wrk[64];
#pragma unroll
    for (int k = 0; k < 64; ++k)
        wrk[k] = Wf[(size_t)(w * 64 + k) * 64 + lane];

    __syncthreads();

#pragma unroll
    for (int i = 0; i < FEAT_NPB; ++i) {
        float a0 = 0.f, a1 = 0.f, a2 = 0.f, a3 = 0.f;
#pragma unroll
        for (int j = 0; j < 16; ++j) {
            const float4 xv = Sx[i][w * 16 + j];   // wave-uniform -> broadcast
            a0 = fmaf(xv.x, wrk[4 * j + 0], a0);
            a1 = fmaf(xv.y, wrk[4 * j + 1], a1);
            a2 = fmaf(xv.z, wrk[4 * j + 2], a2);
            a3 = fmaf(xv.w, wrk[4 * j + 3], a3);
        }
        part[i][w][lane] = (a0 + a1) + (a2 + a3);
    }
    __syncthreads();

#pragma unroll
    for (int j = 0; j < 4; ++j) {
        const int o = t + j * 256;
        const int node = o >> 6, col = o & 63;
        const float r = part[node][0][col] + part[node][1][col]
                      + part[node][2][col] + part[node][3][col] + bf[col];
        h[(size_t)(base + node) * 64 + col] = leaky(r);
    }
}

// ---------------------------------------------------------------------------
// K1: qkvs row (192 floats = 768B): [q f32(64) | k/v fp16 interleaved(128h) |
// skip f32(64)].  Transposed mapping, SGPR h-row broadcast (h is L2-hot),
// coalesced stores.
// ---------------------------------------------------------------------------
#define QKVS_NPB 32   // nodes per block

__global__ __launch_bounds__(256) void k_qkvs(const float* __restrict__ h,
                                              const float* __restrict__ Wt,
                                              const float* __restrict__ bq,
                                              const float* __restrict__ bk,
                                              const float* __restrict__ bv,
                                              const float* __restrict__ bs,
                                              float* __restrict__ qkvs) {
    const int t = threadIdx.x;
    const int lane = t & 63;
    const int sec = __builtin_amdgcn_readfirstlane(t) >> 6;
    const int base = blockIdx.x * QKVS_NPB;

    int m, cidx;
    float bias;
    if (sec == 0)      { m = 0; cidx = lane; bias = bq[lane]; }
    else if (sec == 1) { m = 3; cidx = lane; bias = bs[lane]; }
    else {
        cidx = ((sec - 2) << 5) + (lane >> 1);   // k/v column
        m = 1 + (lane & 1);                      // even lane -> Wk, odd -> Wv
        bias = (lane & 1) ? bv[cidx] : bk[cidx];
    }

    const float4* wb = (const float4*)(Wt + ((size_t)m << 12) + ((size_t)cidx << 6));
    float4 w[16];
#pragma unroll
    for (int j = 0; j < 16; ++j) w[j] = wb[j];

    const int nmax = (base + QKVS_NPB <= NN) ? QKVS_NPB : (NN - base);
    for (int i = 0; i < nmax; ++i) {
        const float* hrow = h + (size_t)(base + i) * 64;   // wave-uniform
        f32x16 ha, hb, hc, hd;
        asm volatile("s_load_dwordx16 %0, %4, 0x0\n\t"
                     "s_load_dwordx16 %1, %4, 0x40\n\t"
                     "s_load_dwordx16 %2, %4, 0x80\n\t"
                     "s_load_dwordx16 %3, %4, 0xc0\n\t"
                     "s_waitcnt lgkmcnt(0)"
                     : "=&s"(ha), "=&s"(hb), "=&s"(hc), "=&s"(hd)
                     : "s"(hrow));
        float a0 = 0.f, a1 = 0.f, a2 = 0.f, a3 = 0.f;
#pragma unroll
        for (int j = 0; j < 4; ++j) {
            a0 = fmaf(ha[4 * j + 0], w[j].x, a0);
            a1 = fmaf(ha[4 * j + 1], w[j].y, a1);
            a2 = fmaf(ha[4 * j + 2], w[j].z, a2);
            a3 = fmaf(ha[4 * j + 3], w[j].w, a3);
        }
#pragma unroll
        for (int j = 0; j < 4; ++j) {
            a0 = fmaf(hb[4 * j + 0], w[4 + j].x, a0);
            a1 = fmaf(hb[4 * j + 1], w[4 + j].y, a1);
            a2 = fmaf(hb[4 * j + 2], w[4 + j].z, a2);
            a3 = fmaf(hb[4 * j + 3], w[4 + j].w, a3);
        }
#pragma unroll
        for (int j = 0; j < 4; ++j) {
            a0 = fmaf(hc[4 * j + 0], w[8 + j].x, a0);
            a1 = fmaf(hc[4 * j + 1], w[8 + j].y, a1);
            a2 = fmaf(hc[4 * j + 2], w[8 + j].z, a2);
            a3 = fmaf(hc[4 * j + 3], w[8 + j].w, a3);
        }
#pragma unroll
        for (int j = 0; j < 4; ++j) {
            a0 = fmaf(hd[4 * j + 0], w[12 + j].x, a0);
            a1 = fmaf(hd[4 * j + 1], w[12 + j].y, a1);
            a2 = fmaf(hd[4 * j + 2], w[12 + j].z, a2);
            a3 = fmaf(hd[4 * j + 3], w[12 + j].w, a3);
        }
        const float val = ((a0 + a1) + (a2 + a3)) + bias;
        float* orow = qkvs + (size_t)(base + i) * 192;
        if (sec == 0) {
            orow[lane] = val;                              // q, f32
        } else if (sec == 1) {
            orow[128 + lane] = val;                        // skip, f32
        } else {
            __half* kvh = (__half*)(orow + 64);
            kvh[((sec - 2) << 6) + lane] = __float2half(val);
        }
    }
}

// ---------------------------------------------------------------------------
// CSR build: histogram -> 3-kernel parallel scan -> scatter
// erec record: 8B = {src:u32, attrs:half2}
// ---------------------------------------------------------------------------
__global__ __launch_bounds__(256) void k_hist(const int* __restrict__ ei,
                                              int* __restrict__ deg) {
    const int e = blockIdx.x * 256 + threadIdx.x;
    if (e >= NE) return;
    atomicAdd(&deg[ei[NE + e]], 1);
}

__global__ __launch_bounds__(256) void k_blocksum(const int* __restrict__ deg,
                                                  int* __restrict__ bsum) {
    __shared__ int sh[256];
    const int t = threadIdx.x;
    const int idx = blockIdx.x * 256 + t;
    sh[t] = (idx < NN) ? deg[idx] : 0;
    __syncthreads();
#pragma unroll
    for (int off = 128; off > 0; off >>= 1) {
        if (t < off) sh[t] += sh[t + off];
        __syncthreads();
    }
    if (t == 0) bsum[blockIdx.x] = sh[0];
}

__global__ __launch_bounds__(256) void k_scanb(const int* __restrict__ bsum,
                                               int* __restrict__ boff) {
    __shared__ int sh[256];
    const int t = threadIdx.x;
    const int v = (t < SCAN_BLOCKS) ? bsum[t] : 0;
    sh[t] = v;
    __syncthreads();
#pragma unroll
    for (int off = 1; off < 256; off <<= 1) {
        const int x = (t >= off) ? sh[t - off] : 0;
        __syncthreads();
        sh[t] += x;
        __syncthreads();
    }
    if (t < SCAN_BLOCKS) boff[t] = sh[t] - v;  // exclusive
}

__global__ __launch_bounds__(256) void k_writeptr(const int* __restrict__ deg,
                                                  const int* __restrict__ boff,
                                                  int* __restrict__ row_ptr,
                                                  int* __restrict__ cursor) {
    __shared__ int sh[256];
    const int t = threadIdx.x;
    const int idx = blockIdx.x * 256 + t;
    const int v = (idx < NN) ? deg[idx] : 0;
    sh[t] = v;
    __syncthreads();
#pragma unroll
    for (int off = 1; off < 256; off <<= 1) {
        const int x = (t >= off) ? sh[t - off] : 0;
        __syncthreads();
        sh[t] += x;
        __syncthreads();
    }
    if (idx < NN) {
        const int r = boff[blockIdx.x] + sh[t] - v;  // exclusive prefix
        row_ptr[idx] = r;
        cursor[idx] = r;
    }
    if (idx == 0) row_ptr[NN] = NE;
}

__global__ __launch_bounds__(256) void k_csr(const int* __restrict__ ei,
                                             const float* __restrict__ eattr,
                                             int* __restrict__ cursor,
                                             uint2* __restrict__ erec) {
    const int e = blockIdx.x * 256 + threadIdx.x;
    if (e >= NE) return;
    const int dst = ei[NE + e];
    const int pos = atomicAdd(&cursor[dst], 1);
    const __half2 a = __floats2half2_rn(eattr[e * 2], eattr[e * 2 + 1]);
    erec[pos] = make_uint2((unsigned)ei[e], *(const unsigned*)&a);
}

// ---------------------------------------------------------------------------
// K2: fused conv, 16-lane edge groups. Wave = 1 destination, 4 groups of 16
// lanes each process one edge; lane p covers channels 4p..4p+3. Dot reduce =
// 4-step shfl_xor (DS pipe). Softmax state per group, merged by 2-step
// butterfly at the end. Edge-feature algebra hoisted (g0,g1 wave-uniform).
// ---------------------------------------------------------------------------
__global__ __launch_bounds__(256) void k_conv(const int* __restrict__ row_ptr,
                                              const uint2* __restrict__ erec,
                                              const float* __restrict__ We,
                                              const float* __restrict__ qkvs,
                                              float* __restrict__ hout) {
    const int t = threadIdx.x;
    const int lane = t & 63;
    const int g = lane >> 4;          // edge-group 0..3
    const int p = lane & 15;          // channel-quarter position
    const int wv = __builtin_amdgcn_readfirstlane(t) >> 6;
    const int d = blockIdx.x * 4 + wv;
    if (d >= NN) return;

    const float* qrow = qkvs + (size_t)d * 192;
    const float4 q4  = *(const float4*)(qrow + 4 * p);
    const float4 w0  = *(const float4*)(We + 4 * p);
    const float4 w1  = *(const float4*)(We + 64 + 4 * p);

    // g0 = q.We0, g1 = q.We1 (channels split across 16 lanes; groups identical)
    float pg0 = q4.x * w0.x + q4.y * w0.y + q4.z * w0.z + q4.w * w0.w;
    float pg1 = q4.x * w1.x + q4.y * w1.y + q4.z * w1.z + q4.w * w1.w;
#pragma unroll
    for (int mask = 1; mask <= 8; mask <<= 1) {
        pg0 += __shfl_xor(pg0, mask);
        pg1 += __shfl_xor(pg1, mask);
    }
    const float g0 = pg0, g1 = pg1;

    const int i0 = row_ptr[d], i1 = row_ptr[d + 1];
    const char* kvbase = (const char*)qkvs + 256 + ((size_t)p << 4);

    float m = -1e30f, l = 0.f, S1 = 0.f, S2 = 0.f;
    float4 acc = make_float4(0.f, 0.f, 0.f, 0.f);

#pragma unroll 2
    for (int i = i0 + g; i < i1; i += 4) {
        const uint2 r = erec[i];
        const __half2 ah = *(const __half2*)&r.y;
        const float a0 = __low2float(ah), a1 = __high2float(ah);
        const float4 kvl = *(const float4*)(kvbase + (size_t)r.x * 768);
        const __half2* hv = (const __half2*)&kvl;
        const float kf0 = __low2float(hv[0]), vf0 = __high2float(hv[0]);
        const float kf1 = __low2float(hv[1]), vf1 = __high2float(hv[1]);
        const float kf2 = __low2float(hv[2]), vf2 = __high2float(hv[2]);
        const float kf3 = __low2float(hv[3]), vf3 = __high2float(hv[3]);
        float dot = q4.x * kf0 + q4.y * kf1 + q4.z * kf2 + q4.w * kf3;
        dot += __shfl_xor(dot, 1);
        dot += __shfl_xor(dot, 2);
        dot += __shfl_xor(dot, 4);
        dot += __shfl_xor(dot, 8);
        const float P = (dot + g0 * a0 + g1 * a1) * 0.125f;
        const float mn = fmaxf(m, P);
        const float s = __expf(m - mn);
        const float e = __expf(P - mn);
        l = l * s + e;
        acc.x = acc.x * s + vf0 * e;
        acc.y = acc.y * s + vf1 * e;
        acc.z = acc.z * s + vf2 * e;
        acc.w = acc.w * s + vf3 * e;
        S1 = S1 * s + a0 * e;
        S2 = S2 * s + a1 * e;
        m = mn;
    }

    // merge the 4 groups (lane bits 4 and 5): softmax-merge butterfly
#pragma unroll
    for (int mask = 16; mask <= 32; mask <<= 1) {
        const float mo  = __shfl_xor(m, mask);
        const float lo  = __shfl_xor(l, mask);
        const float axo = __shfl_xor(acc.x, mask);
        const float ayo = __shfl_xor(acc.y, mask);
        const float azo = __shfl_xor(acc.z, mask);
        const float awo = __shfl_xor(acc.w, mask);
        const float S1o = __shfl_xor(S1, mask);
        const float S2o = __shfl_xor(S2, mask);
        const float mn = fmaxf(m, mo);
        const float sA = __expf(m - mn);
        const float sB = __expf(mo - mn);
        l     = l * sA + lo * sB;
        acc.x = acc.x * sA + axo * sB;
        acc.y = acc.y * sA + ayo * sB;
        acc.z = acc.z * sA + azo * sB;
        acc.w = acc.w * sA + awo * sB;
        S1    = S1 * sA + S1o * sB;
        S2    = S2 * sA + S2o * sB;
        m = mn;
    }

    if (lane < 16) {
        const float inv = (l > 0.f) ? 1.f / l : 0.f;
        const float4 sk = *(const float4*)(qrow + 128 + 4 * p);
        float4 r;
        r.x = leaky((acc.x + S1 * w0.x + S2 * w1.x) * inv + sk.x);
        r.y = leaky((acc.y + S1 * w0.y + S2 * w1.y) * inv + sk.y);
        r.z = leaky((acc.z + S1 * w0.z + S2 * w1.z) * inv + sk.z);
        r.w = leaky((acc.w + S1 * w0.w + S2 * w1.w) * inv + sk.w);
        *(float4*)(hout + (size_t)d * C + 4 * p) = r;
    }
}

extern "C" void kernel_launch(void* const* d_in, const int* in_sizes, int n_in,
                              void* d_out, int out_size, void* d_ws, size_t ws_size,
                              hipStream_t stream) {
    const float* x     = (const float*)d_in[0];
    const int*   ei    = (const int*)d_in[1];
    const float* eattr = (const float*)d_in[2];
    const float* Wf    = (const float*)d_in[3];
    const float* bf    = (const float*)d_in[4];
    const float* Wq    = (const float*)d_in[5];
    const float* bq    = (const float*)d_in[6];
    const float* Wk    = (const float*)d_in[7];
    const float* bk    = (const float*)d_in[8];
    const float* Wv    = (const float*)d_in[9];
    const float* bv    = (const float*)d_in[10];
    const float* We    = (const float*)d_in[11];
    const float* Ws    = (const float*)d_in[12];
    const float* bs    = (const float*)d_in[13];
    float* out = (float*)d_out;

    // workspace layout
    char* p = (char*)d_ws;
    float*  h       = (float*)p;  p += (size_t)NN * C * 4;        // 12.8 MB
    float*  qkvs    = (float*)p;  p += (size_t)NN * 192 * 4;      // 38.4 MB
    float*  Wt      = (float*)p;  p += (size_t)4 * 64 * 64 * 4;   // 64 KB
    int*    deg     = (int*)p;    p += (size_t)NN * 4;
    int*    row_ptr = (int*)p;    p += (size_t)(NN + 1) * 4;
    int*    cursor  = (int*)p;    p += (size_t)NN * 4;
    int*    bsum    = (int*)p;    p += (size_t)SCAN_BLOCKS * 4;
    int*    boff    = (int*)p;    p += (size_t)SCAN_BLOCKS * 4;
    uint2*  erec    = (uint2*)p;  p += (size_t)NE * 8;            // 6.4 MB

    // One-time per call: weight transpose + CSR build
    k_tw<<<64, 256, 0, stream>>>(Wq, Wk, Wv, Ws, Wt);
    hipMemsetAsync(deg, 0, (size_t)NN * 4, stream);
    k_hist<<<(NE + 255) / 256, 256, 0, stream>>>(ei, deg);
    k_blocksum<<<SCAN_BLOCKS, 256, 0, stream>>>(deg, bsum);
    k_scanb<<<1, 256, 0, stream>>>(bsum, boff);
    k_writeptr<<<SCAN_BLOCKS, 256, 0, stream>>>(deg, boff, row_ptr, cursor);
    k_csr<<<(NE + 255) / 256, 256, 0, stream>>>(ei, eattr, cursor, erec);

    const int feat_grid = NN / FEAT_NPB;                    // 3125 exact
    const int qkvs_grid = (NN + QKVS_NPB - 1) / QKVS_NPB;   // 1563

    k_feat<<<feat_grid, 256, 0, stream>>>(x, Wf, bf, h);

    for (int layer = 0; layer < 3; ++layer) {
        k_qkvs<<<qkvs_grid, 256, 0, stream>>>(h, Wt, bq, bk, bv, bs, qkvs);
        float* hout = (layer == 2) ? out : h;
        k_conv<<<(NN + 3) / 4, 256, 0, stream>>>(row_ptr, erec, We, qkvs, hout);
    }
}

// Round 6
// 488.875 us; speedup vs baseline: 2.2611x; 1.0170x over previous
//
#include <hip/hip_runtime.h>
#include <hip/hip_fp16.h>

#define NN 50000
#define NE 800000
#define FIN 256
#define C 64
#define NEG_SLOPE 0.01f
#define SCAN_BLOCKS ((NN + 255) / 256)   // 196
#define CSR_CHUNKS (NE / 256)            // 3125 exact

typedef float f32x16 __attribute__((ext_vector_type(16)));

__device__ __forceinline__ float leaky(float v) { return v > 0.f ? v : NEG_SLOPE * v; }

// ---------------------------------------------------------------------------
// Weight transpose: Wt[m][c][k] = W_m[k][c], m in {q,k,v,skip}. 16384 elems.
// ---------------------------------------------------------------------------
__global__ __launch_bounds__(256) void k_tw(const float* __restrict__ Wq,
                                            const float* __restrict__ Wk,
                                            const float* __restrict__ Wv,
                                            const float* __restrict__ Ws,
                                            float* __restrict__ Wt) {
    const int idx = blockIdx.x * 256 + threadIdx.x;
    if (idx >= 4 * 64 * 64) return;
    const int m = idx >> 12, r = idx & 4095, c = r >> 6, k = r & 63;
    const float* W = (m == 0) ? Wq : (m == 1) ? Wk : (m == 2) ? Wv : Ws;
    Wt[idx] = W[k * 64 + c];
}

// ---------------------------------------------------------------------------
// K0: h = leaky_relu(x @ Wf + bf).
// x is COLD (51.2 MB, read once) -> stage via the VECTOR path into LDS
// (coalesced float4), broadcast to lanes with wave-uniform ds_read_b128.
// lane = output column, wave = k-quarter, weights per-lane from Wf.
// ---------------------------------------------------------------------------
#define FEAT_NPB 16   // nodes per block

__global__ __launch_bounds__(256) void k_feat(const float* __restrict__ x,
                                              const float* __restrict__ Wf,
                                              const float* __restrict__ bf,
                                              float* __restrict__ h) {
    __shared__ float4 Sx[FEAT_NPB][64];       // 16 KB x-tile [node][col4]
    __shared__ float part[FEAT_NPB][4][64];   // 16 KB partial sums
    const int t = threadIdx.x;
    const int lane = t & 63;
    const int w = __builtin_amdgcn_readfirstlane(t) >> 6;   // k-quarter
    const int base = blockIdx.x * FEAT_NPB;

    const float4* x4 = (const float4*)x;
#pragma unroll
    for (int i = 0; i < 4; ++i) {
        const int idx = t + i * 256;
        const int row = idx >> 6, c4 = idx & 63;
        Sx[row][c4] = x4[(size_t)(base + row) * 64 + c4];
    }

    float wrk[64];
#pragma unroll
    for (int k = 0; k < 64; ++k)
        wrk[k] = Wf[(size_t)(w * 64 + k) * 64 + lane];

    __syncthreads();

#pragma unroll
    for (int i = 0; i < FEAT_NPB; ++i) {
        float a0 = 0.f, a1 = 0.f, a2 = 0.f, a3 = 0.f;
#pragma unroll
        for (int j = 0; j < 16; ++j) {
            const float4 xv = Sx[i][w * 16 + j];   // wave-uniform -> broadcast
            a0 = fmaf(xv.x, wrk[4 * j + 0], a0);
            a1 = fmaf(xv.y, wrk[4 * j + 1], a1);
            a2 = fmaf(xv.z, wrk[4 * j + 2], a2);
            a3 = fmaf(xv.w, wrk[4 * j + 3], a3);
        }
        part[i][w][lane] = (a0 + a1) + (a2 + a3);
    }
    __syncthreads();

#pragma unroll
    for (int j = 0; j < 4; ++j) {
        const int o = t + j * 256;
        const int node = o >> 6, col = o & 63;
        const float r = part[node][0][col] + part[node][1][col]
                      + part[node][2][col] + part[node][3][col] + bf[col];
        h[(size_t)(base + node) * 64 + col] = leaky(r);
    }
}

// ---------------------------------------------------------------------------
// K1: qkvs row (192 floats = 768B): [q f32(64) | k/v fp16 interleaved(128h) |
// skip f32(64)].  Transposed mapping, SGPR h-row broadcast (h is L2-hot),
// coalesced stores.
// ---------------------------------------------------------------------------
#define QKVS_NPB 32   // nodes per block

__global__ __launch_bounds__(256) void k_qkvs(const float* __restrict__ h,
                                              const float* __restrict__ Wt,
                                              const float* __restrict__ bq,
                                              const float* __restrict__ bk,
                                              const float* __restrict__ bv,
                                              const float* __restrict__ bs,
                                              float* __restrict__ qkvs) {
    const int t = threadIdx.x;
    const int lane = t & 63;
    const int sec = __builtin_amdgcn_readfirstlane(t) >> 6;
    const int base = blockIdx.x * QKVS_NPB;

    int m, cidx;
    float bias;
    if (sec == 0)      { m = 0; cidx = lane; bias = bq[lane]; }
    else if (sec == 1) { m = 3; cidx = lane; bias = bs[lane]; }
    else {
        cidx = ((sec - 2) << 5) + (lane >> 1);   // k/v column
        m = 1 + (lane & 1);                      // even lane -> Wk, odd -> Wv
        bias = (lane & 1) ? bv[cidx] : bk[cidx];
    }

    const float4* wb = (const float4*)(Wt + ((size_t)m << 12) + ((size_t)cidx << 6));
    float4 w[16];
#pragma unroll
    for (int j = 0; j < 16; ++j) w[j] = wb[j];

    const int nmax = (base + QKVS_NPB <= NN) ? QKVS_NPB : (NN - base);
    for (int i = 0; i < nmax; ++i) {
        const float* hrow = h + (size_t)(base + i) * 64;   // wave-uniform
        f32x16 ha, hb, hc, hd;
        asm volatile("s_load_dwordx16 %0, %4, 0x0\n\t"
                     "s_load_dwordx16 %1, %4, 0x40\n\t"
                     "s_load_dwordx16 %2, %4, 0x80\n\t"
                     "s_load_dwordx16 %3, %4, 0xc0\n\t"
                     "s_waitcnt lgkmcnt(0)"
                     : "=&s"(ha), "=&s"(hb), "=&s"(hc), "=&s"(hd)
                     : "s"(hrow));
        float a0 = 0.f, a1 = 0.f, a2 = 0.f, a3 = 0.f;
#pragma unroll
        for (int j = 0; j < 4; ++j) {
            a0 = fmaf(ha[4 * j + 0], w[j].x, a0);
            a1 = fmaf(ha[4 * j + 1], w[j].y, a1);
            a2 = fmaf(ha[4 * j + 2], w[j].z, a2);
            a3 = fmaf(ha[4 * j + 3], w[j].w, a3);
        }
#pragma unroll
        for (int j = 0; j < 4; ++j) {
            a0 = fmaf(hb[4 * j + 0], w[4 + j].x, a0);
            a1 = fmaf(hb[4 * j + 1], w[4 + j].y, a1);
            a2 = fmaf(hb[4 * j + 2], w[4 + j].z, a2);
            a3 = fmaf(hb[4 * j + 3], w[4 + j].w, a3);
        }
#pragma unroll
        for (int j = 0; j < 4; ++j) {
            a0 = fmaf(hc[4 * j + 0], w[8 + j].x, a0);
            a1 = fmaf(hc[4 * j + 1], w[8 + j].y, a1);
            a2 = fmaf(hc[4 * j + 2], w[8 + j].z, a2);
            a3 = fmaf(hc[4 * j + 3], w[8 + j].w, a3);
        }
#pragma unroll
        for (int j = 0; j < 4; ++j) {
            a0 = fmaf(hd[4 * j + 0], w[12 + j].x, a0);
            a1 = fmaf(hd[4 * j + 1], w[12 + j].y, a1);
            a2 = fmaf(hd[4 * j + 2], w[12 + j].z, a2);
            a3 = fmaf(hd[4 * j + 3], w[12 + j].w, a3);
        }
        const float val = ((a0 + a1) + (a2 + a3)) + bias;
        float* orow = qkvs + (size_t)(base + i) * 192;
        if (sec == 0) {
            orow[lane] = val;                              // q, f32
        } else if (sec == 1) {
            orow[128 + lane] = val;                        // skip, f32
        } else {
            __half* kvh = (__half*)(orow + 64);
            kvh[((sec - 2) << 6) + lane] = __float2half(val);
        }
    }
}

// ---------------------------------------------------------------------------
// CSR build: histogram -> 3-kernel parallel scan -> XCD-partitioned scatter
// erec record: 8B = {src:u32, attrs:half2}
// ---------------------------------------------------------------------------
__global__ __launch_bounds__(256) void k_hist(const int* __restrict__ ei,
                                              int* __restrict__ deg) {
    const int e = blockIdx.x * 256 + threadIdx.x;
    if (e >= NE) return;
    atomicAdd(&deg[ei[NE + e]], 1);
}

__global__ __launch_bounds__(256) void k_blocksum(const int* __restrict__ deg,
                                                  int* __restrict__ bsum) {
    __shared__ int sh[256];
    const int t = threadIdx.x;
    const int idx = blockIdx.x * 256 + t;
    sh[t] = (idx < NN) ? deg[idx] : 0;
    __syncthreads();
#pragma unroll
    for (int off = 128; off > 0; off >>= 1) {
        if (t < off) sh[t] += sh[t + off];
        __syncthreads();
    }
    if (t == 0) bsum[blockIdx.x] = sh[0];
}

__global__ __launch_bounds__(256) void k_scanb(const int* __restrict__ bsum,
                                               int* __restrict__ boff) {
    __shared__ int sh[256];
    const int t = threadIdx.x;
    const int v = (t < SCAN_BLOCKS) ? bsum[t] : 0;
    sh[t] = v;
    __syncthreads();
#pragma unroll
    for (int off = 1; off < 256; off <<= 1) {
        const int x = (t >= off) ? sh[t - off] : 0;
        __syncthreads();
        sh[t] += x;
        __syncthreads();
    }
    if (t < SCAN_BLOCKS) boff[t] = sh[t] - v;  // exclusive
}

__global__ __launch_bounds__(256) void k_writeptr(const int* __restrict__ deg,
                                                  const int* __restrict__ boff,
                                                  int* __restrict__ row_ptr,
                                                  int* __restrict__ cursor) {
    __shared__ int sh[256];
    const int t = threadIdx.x;
    const int idx = blockIdx.x * 256 + t;
    const int v = (idx < NN) ? deg[idx] : 0;
    sh[t] = v;
    __syncthreads();
#pragma unroll
    for (int off = 1; off < 256; off <<= 1) {
        const int x = (t >= off) ? sh[t - off] : 0;
        __syncthreads();
        sh[t] += x;
        __syncthreads();
    }
    if (idx < NN) {
        const int r = boff[blockIdx.x] + sh[t] - v;  // exclusive prefix
        row_ptr[idx] = r;
        cursor[idx] = r;
    }
    if (idx == 0) row_ptr[NN] = NE;
}

// XCD-ownership-partitioned scatter: 8 filter-replicas per 256-edge chunk.
// Replica x (blockIdx & 7, round-robin = XCD x) keeps only edges whose erec
// position range (row_ptr[dst] / (NE/8)) is x. All writes to a given erec
// line then come from one XCD -> full-line single writebacks instead of
// 8-way partial-dirty cross-XCD writeback amplification. Correct under ANY
// block->XCD mapping (each edge processed by exactly one (chunk,owner) block).
__global__ __launch_bounds__(256) void k_csr(const int* __restrict__ ei,
                                             const float* __restrict__ eattr,
                                             const int* __restrict__ row_ptr,
                                             int* __restrict__ cursor,
                                             uint2* __restrict__ erec) {
    const int chunk = blockIdx.x >> 3;
    const unsigned myx = blockIdx.x & 7;
    const int e = chunk * 256 + threadIdx.x;     // NE = 3125*256 exact
    const int dst = ei[NE + e];
    const int rp = row_ptr[dst];
    const unsigned owner = (unsigned)rp / (NE / 8u);
    if (owner != myx) return;
    const int pos = atomicAdd(&cursor[dst], 1);
    const __half2 a = __floats2half2_rn(eattr[e * 2], eattr[e * 2 + 1]);
    erec[pos] = make_uint2((unsigned)ei[e], *(const unsigned*)&a);
}

// ---------------------------------------------------------------------------
// K2: fused conv, 16-lane edge groups. Wave = 1 destination, 4 groups of 16
// lanes each process one edge; lane p covers channels 4p..4p+3. Dot reduce =
// 4-step shfl_xor (DS pipe). Softmax state per group, merged by 2-step
// butterfly at the end. Edge-feature algebra hoisted (g0,g1 wave-uniform).
// ---------------------------------------------------------------------------
__global__ __launch_bounds__(256) void k_conv(const int* __restrict__ row_ptr,
                                              const uint2* __restrict__ erec,
                                              const float* __restrict__ We,
                                              const float* __restrict__ qkvs,
                                              float* __restrict__ hout) {
    const int t = threadIdx.x;
    const int lane = t & 63;
    const int g = lane >> 4;          // edge-group 0..3
    const int p = lane & 15;          // channel-quarter position
    const int wv = __builtin_amdgcn_readfirstlane(t) >> 6;
    const int d = blockIdx.x * 4 + wv;
    if (d >= NN) return;

    const float* qrow = qkvs + (size_t)d * 192;
    const float4 q4  = *(const float4*)(qrow + 4 * p);
    const float4 w0  = *(const float4*)(We + 4 * p);
    const float4 w1  = *(const float4*)(We + 64 + 4 * p);

    // g0 = q.We0, g1 = q.We1 (channels split across 16 lanes; groups identical)
    float pg0 = q4.x * w0.x + q4.y * w0.y + q4.z * w0.z + q4.w * w0.w;
    float pg1 = q4.x * w1.x + q4.y * w1.y + q4.z * w1.z + q4.w * w1.w;
#pragma unroll
    for (int mask = 1; mask <= 8; mask <<= 1) {
        pg0 += __shfl_xor(pg0, mask);
        pg1 += __shfl_xor(pg1, mask);
    }
    const float g0 = pg0, g1 = pg1;

    const int i0 = row_ptr[d], i1 = row_ptr[d + 1];
    const char* kvbase = (const char*)qkvs + 256 + ((size_t)p << 4);

    float m = -1e30f, l = 0.f, S1 = 0.f, S2 = 0.f;
    float4 acc = make_float4(0.f, 0.f, 0.f, 0.f);

#pragma unroll 2
    for (int i = i0 + g; i < i1; i += 4) {
        const uint2 r = erec[i];
        const __half2 ah = *(const __half2*)&r.y;
        const float a0 = __low2float(ah), a1 = __high2float(ah);
        const float4 kvl = *(const float4*)(kvbase + (size_t)r.x * 768);
        const __half2* hv = (const __half2*)&kvl;
        const float kf0 = __low2float(hv[0]), vf0 = __high2float(hv[0]);
        const float kf1 = __low2float(hv[1]), vf1 = __high2float(hv[1]);
        const float kf2 = __low2float(hv[2]), vf2 = __high2float(hv[2]);
        const float kf3 = __low2float(hv[3]), vf3 = __high2float(hv[3]);
        float dot = q4.x * kf0 + q4.y * kf1 + q4.z * kf2 + q4.w * kf3;
        dot += __shfl_xor(dot, 1);
        dot += __shfl_xor(dot, 2);
        dot += __shfl_xor(dot, 4);
        dot += __shfl_xor(dot, 8);
        const float P = (dot + g0 * a0 + g1 * a1) * 0.125f;
        const float mn = fmaxf(m, P);
        const float s = __expf(m - mn);
        const float e = __expf(P - mn);
        l = l * s + e;
        acc.x = acc.x * s + vf0 * e;
        acc.y = acc.y * s + vf1 * e;
        acc.z = acc.z * s + vf2 * e;
        acc.w = acc.w * s + vf3 * e;
        S1 = S1 * s + a0 * e;
        S2 = S2 * s + a1 * e;
        m = mn;
    }

    // merge the 4 groups (lane bits 4 and 5): softmax-merge butterfly
#pragma unroll
    for (int mask = 16; mask <= 32; mask <<= 1) {
        const float mo  = __shfl_xor(m, mask);
        const float lo  = __shfl_xor(l, mask);
        const float axo = __shfl_xor(acc.x, mask);
        const float ayo = __shfl_xor(acc.y, mask);
        const float azo = __shfl_xor(acc.z, mask);
        const float awo = __shfl_xor(acc.w, mask);
        const float S1o = __shfl_xor(S1, mask);
        const float S2o = __shfl_xor(S2, mask);
        const float mn = fmaxf(m, mo);
        const float sA = __expf(m - mn);
        const float sB = __expf(mo - mn);
        l     = l * sA + lo * sB;
        acc.x = acc.x * sA + axo * sB;
        acc.y = acc.y * sA + ayo * sB;
        acc.z = acc.z * sA + azo * sB;
        acc.w = acc.w * sA + awo * sB;
        S1    = S1 * sA + S1o * sB;
        S2    = S2 * sA + S2o * sB;
        m = mn;
    }

    if (lane < 16) {
        const float inv = (l > 0.f) ? 1.f / l : 0.f;
        const float4 sk = *(const float4*)(qrow + 128 + 4 * p);
        float4 r;
        r.x = leaky((acc.x + S1 * w0.x + S2 * w1.x) * inv + sk.x);
        r.y = leaky((acc.y + S1 * w0.y + S2 * w1.y) * inv + sk.y);
        r.z = leaky((acc.z + S1 * w0.z + S2 * w1.z) * inv + sk.z);
        r.w = leaky((acc.w + S1 * w0.w + S2 * w1.w) * inv + sk.w);
        *(float4*)(hout + (size_t)d * C + 4 * p) = r;
    }
}

extern "C" void kernel_launch(void* const* d_in, const int* in_sizes, int n_in,
                              void* d_out, int out_size, void* d_ws, size_t ws_size,
                              hipStream_t stream) {
    const float* x     = (const float*)d_in[0];
    const int*   ei    = (const int*)d_in[1];
    const float* eattr = (const float*)d_in[2];
    const float* Wf    = (const float*)d_in[3];
    const float* bf    = (const float*)d_in[4];
    const float* Wq    = (const float*)d_in[5];
    const float* bq    = (const float*)d_in[6];
    const float* Wk    = (const float*)d_in[7];
    const float* bk    = (const float*)d_in[8];
    const float* Wv    = (const float*)d_in[9];
    const float* bv    = (const float*)d_in[10];
    const float* We    = (const float*)d_in[11];
    const float* Ws    = (const float*)d_in[12];
    const float* bs    = (const float*)d_in[13];
    float* out = (float*)d_out;

    // workspace layout
    char* p = (char*)d_ws;
    float*  h       = (float*)p;  p += (size_t)NN * C * 4;        // 12.8 MB
    float*  qkvs    = (float*)p;  p += (size_t)NN * 192 * 4;      // 38.4 MB
    float*  Wt      = (float*)p;  p += (size_t)4 * 64 * 64 * 4;   // 64 KB
    int*    deg     = (int*)p;    p += (size_t)NN * 4;
    int*    row_ptr = (int*)p;    p += (size_t)(NN + 1) * 4;
    int*    cursor  = (int*)p;    p += (size_t)NN * 4;
    int*    bsum    = (int*)p;    p += (size_t)SCAN_BLOCKS * 4;
    int*    boff    = (int*)p;    p += (size_t)SCAN_BLOCKS * 4;
    uint2*  erec    = (uint2*)p;  p += (size_t)NE * 8;            // 6.4 MB

    // One-time per call: weight transpose + CSR build
    k_tw<<<64, 256, 0, stream>>>(Wq, Wk, Wv, Ws, Wt);
    hipMemsetAsync(deg, 0, (size_t)NN * 4, stream);
    k_hist<<<CSR_CHUNKS, 256, 0, stream>>>(ei, deg);
    k_blocksum<<<SCAN_BLOCKS, 256, 0, stream>>>(deg, bsum);
    k_scanb<<<1, 256, 0, stream>>>(bsum, boff);
    k_writeptr<<<SCAN_BLOCKS, 256, 0, stream>>>(deg, boff, row_ptr, cursor);
    k_csr<<<CSR_CHUNKS * 8, 256, 0, stream>>>(ei, eattr, row_ptr, cursor, erec);

    const int feat_grid = NN / FEAT_NPB;                    // 3125 exact
    const int qkvs_grid = (NN + QKVS_NPB - 1) / QKVS_NPB;   // 1563

    k_feat<<<feat_grid, 256, 0, stream>>>(x, Wf, bf, h);

    for (int layer = 0; layer < 3; ++layer) {
        k_qkvs<<<qkvs_grid, 256, 0, stream>>>(h, Wt, bq, bk, bv, bs, qkvs);
        float* hout = (layer == 2) ? out : h;
        k_conv<<<(NN + 3) / 4, 256, 0, stream>>>(row_ptr, erec, We, qkvs, hout);
    }
}

// Round 7
// 482.643 us; speedup vs baseline: 2.2903x; 1.0129x over previous
//
#include <hip/hip_runtime.h>
#include <hip/hip_fp16.h>

#define NN 50000
#define NE 800000
#define FIN 256
#define C 64
#define NEG_SLOPE 0.01f
#define SCAN_BLOCKS ((NN + 255) / 256)   // 196
#define CSR_CHUNKS (NE / 256)            // 3125 exact

typedef float f32x16 __attribute__((ext_vector_type(16)));

__device__ __forceinline__ float leaky(float v) { return v > 0.f ? v : NEG_SLOPE * v; }

// ---------------------------------------------------------------------------
// Weight transpose: Wt[m][c][k] = W_m[k][c], m in {q,k,v,skip}. 16384 elems.
// ---------------------------------------------------------------------------
__global__ __launch_bounds__(256) void k_tw(const float* __restrict__ Wq,
                                            const float* __restrict__ Wk,
                                            const float* __restrict__ Wv,
                                            const float* __restrict__ Ws,
                                            float* __restrict__ Wt) {
    const int idx = blockIdx.x * 256 + threadIdx.x;
    if (idx >= 4 * 64 * 64) return;
    const int m = idx >> 12, r = idx & 4095, c = r >> 6, k = r & 63;
    const float* W = (m == 0) ? Wq : (m == 1) ? Wk : (m == 2) ? Wv : Ws;
    Wt[idx] = W[k * 64 + c];
}

// ---------------------------------------------------------------------------
// K0: h = leaky_relu(x @ Wf + bf).
// lane = node (per-lane-DISTINCT LDS reads of x: 1 ds_read_b128 -> 64 FMAs),
// wave = col-quarter (16 cols/thread in registers), weights broadcast via
// s_load_dwordx16 (W is 64KB, L2/K$-hot -> short scalar latency).
// x staged in 2 phases of 128 k; padded [64][33] float4 tile = bank-even
// column-slice reads. Epilogue restaged through LDS for coalesced stores.
// ---------------------------------------------------------------------------
__global__ __launch_bounds__(256) void k_feat(const float* __restrict__ x,
                                              const float* __restrict__ Wf,
                                              const float* __restrict__ bf,
                                              float* __restrict__ h) {
    __shared__ float4 Sx[64][33];   // 33.8 KB; +1 pad -> banks 4*(lane+j) even
    const int t = threadIdx.x;
    const int lane = t & 63;
    const int q = __builtin_amdgcn_readfirstlane(t) >> 6;   // col-quarter
    const int base = blockIdx.x * 64;

    const float4* x4 = (const float4*)x;
    float4 acc[4];
#pragma unroll
    for (int cp = 0; cp < 4; ++cp) acc[cp] = make_float4(0.f, 0.f, 0.f, 0.f);

#define FRAG(wreg, xs)                                                      \
    acc[0].x = fmaf(xs, wreg[0],  acc[0].x);                                \
    acc[0].y = fmaf(xs, wreg[1],  acc[0].y);                                \
    acc[0].z = fmaf(xs, wreg[2],  acc[0].z);                                \
    acc[0].w = fmaf(xs, wreg[3],  acc[0].w);                                \
    acc[1].x = fmaf(xs, wreg[4],  acc[1].x);                                \
    acc[1].y = fmaf(xs, wreg[5],  acc[1].y);                                \
    acc[1].z = fmaf(xs, wreg[6],  acc[1].z);                                \
    acc[1].w = fmaf(xs, wreg[7],  acc[1].w);                                \
    acc[2].x = fmaf(xs, wreg[8],  acc[2].x);                                \
    acc[2].y = fmaf(xs, wreg[9],  acc[2].y);                                \
    acc[2].z = fmaf(xs, wreg[10], acc[2].z);                                \
    acc[2].w = fmaf(xs, wreg[11], acc[2].w);                                \
    acc[3].x = fmaf(xs, wreg[12], acc[3].x);                                \
    acc[3].y = fmaf(xs, wreg[13], acc[3].y);                                \
    acc[3].z = fmaf(xs, wreg[14], acc[3].z);                                \
    acc[3].w = fmaf(xs, wreg[15], acc[3].w);

    for (int ph = 0; ph < 2; ++ph) {
        // stage 64 nodes x 128 k (32 float4/row); 8 coalesced float4/thread
#pragma unroll
        for (int i = 0; i < 8; ++i) {
            const int idx = t + i * 256;
            const int row = idx >> 5, c = idx & 31;
            int nn = base + row; if (nn >= NN) nn = NN - 1;
            Sx[row][c] = x4[(size_t)nn * 64 + ph * 32 + c];
        }
        __syncthreads();

        const float* wbase = Wf + (size_t)(ph * 128) * 64 + q * 16;
#pragma unroll
        for (int j = 0; j < 32; ++j) {
            const float4 xv = Sx[lane][j];            // per-lane distinct row
            const float* wrow = wbase + (size_t)j * 256;  // W[4j+0][q*16]
            f32x16 w0_, w1_, w2_, w3_;
            asm volatile("s_load_dwordx16 %0, %4, 0x0\n\t"
                         "s_load_dwordx16 %1, %4, 0x100\n\t"
                         "s_load_dwordx16 %2, %4, 0x200\n\t"
                         "s_load_dwordx16 %3, %4, 0x300\n\t"
                         "s_waitcnt lgkmcnt(0)"
                         : "=&s"(w0_), "=&s"(w1_), "=&s"(w2_), "=&s"(w3_)
                         : "s"(wrow));
            FRAG(w0_, xv.x)
            FRAG(w1_, xv.y)
            FRAG(w2_, xv.z)
            FRAG(w3_, xv.w)
        }
        __syncthreads();   // before Sx reuse (next phase stage / out-stage)
    }
#undef FRAG

    // out-stage: reuse Sx as padded [64][17] float4 for coalesced stores
    float4* O = (float4*)Sx;
    const float4* bf4 = (const float4*)bf;
#pragma unroll
    for (int cp = 0; cp < 4; ++cp) {
        const float4 b = bf4[q * 4 + cp];
        float4 r;
        r.x = leaky(acc[cp].x + b.x); r.y = leaky(acc[cp].y + b.y);
        r.z = leaky(acc[cp].z + b.z); r.w = leaky(acc[cp].w + b.w);
        O[lane * 17 + q * 4 + cp] = r;
    }
    __syncthreads();
#pragma unroll
    for (int i = 0; i < 4; ++i) {
        const int idx = t + i * 256;
        const int row = idx >> 4, c = idx & 15;
        const int nn = base + row;
        if (nn < NN) ((float4*)h)[(size_t)nn * 16 + c] = O[row * 17 + c];
    }
}

// ---------------------------------------------------------------------------
// K1: qkvs row (192 floats = 768B): [q f32(64) | k/v fp16 interleaved(128h) |
// skip f32(64)].  Transposed mapping, SGPR h-row broadcast (h is L2-hot),
// coalesced stores.
// ---------------------------------------------------------------------------
#define QKVS_NPB 32   // nodes per block

__global__ __launch_bounds__(256) void k_qkvs(const float* __restrict__ h,
                                              const float* __restrict__ Wt,
                                              const float* __restrict__ bq,
                                              const float* __restrict__ bk,
                                              const float* __restrict__ bv,
                                              const float* __restrict__ bs,
                                              float* __restrict__ qkvs) {
    const int t = threadIdx.x;
    const int lane = t & 63;
    const int sec = __builtin_amdgcn_readfirstlane(t) >> 6;
    const int base = blockIdx.x * QKVS_NPB;

    int m, cidx;
    float bias;
    if (sec == 0)      { m = 0; cidx = lane; bias = bq[lane]; }
    else if (sec == 1) { m = 3; cidx = lane; bias = bs[lane]; }
    else {
        cidx = ((sec - 2) << 5) + (lane >> 1);   // k/v column
        m = 1 + (lane & 1);                      // even lane -> Wk, odd -> Wv
        bias = (lane & 1) ? bv[cidx] : bk[cidx];
    }

    const float4* wb = (const float4*)(Wt + ((size_t)m << 12) + ((size_t)cidx << 6));
    float4 w[16];
#pragma unroll
    for (int j = 0; j < 16; ++j) w[j] = wb[j];

    const int nmax = (base + QKVS_NPB <= NN) ? QKVS_NPB : (NN - base);
    for (int i = 0; i < nmax; ++i) {
        const float* hrow = h + (size_t)(base + i) * 64;   // wave-uniform
        f32x16 ha, hb, hc, hd;
        asm volatile("s_load_dwordx16 %0, %4, 0x0\n\t"
                     "s_load_dwordx16 %1, %4, 0x40\n\t"
                     "s_load_dwordx16 %2, %4, 0x80\n\t"
                     "s_load_dwordx16 %3, %4, 0xc0\n\t"
                     "s_waitcnt lgkmcnt(0)"
                     : "=&s"(ha), "=&s"(hb), "=&s"(hc), "=&s"(hd)
                     : "s"(hrow));
        float a0 = 0.f, a1 = 0.f, a2 = 0.f, a3 = 0.f;
#pragma unroll
        for (int j = 0; j < 4; ++j) {
            a0 = fmaf(ha[4 * j + 0], w[j].x, a0);
            a1 = fmaf(ha[4 * j + 1], w[j].y, a1);
            a2 = fmaf(ha[4 * j + 2], w[j].z, a2);
            a3 = fmaf(ha[4 * j + 3], w[j].w, a3);
        }
#pragma unroll
        for (int j = 0; j < 4; ++j) {
            a0 = fmaf(hb[4 * j + 0], w[4 + j].x, a0);
            a1 = fmaf(hb[4 * j + 1], w[4 + j].y, a1);
            a2 = fmaf(hb[4 * j + 2], w[4 + j].z, a2);
            a3 = fmaf(hb[4 * j + 3], w[4 + j].w, a3);
        }
#pragma unroll
        for (int j = 0; j < 4; ++j) {
            a0 = fmaf(hc[4 * j + 0], w[8 + j].x, a0);
            a1 = fmaf(hc[4 * j + 1], w[8 + j].y, a1);
            a2 = fmaf(hc[4 * j + 2], w[8 + j].z, a2);
            a3 = fmaf(hc[4 * j + 3], w[8 + j].w, a3);
        }
#pragma unroll
        for (int j = 0; j < 4; ++j) {
            a0 = fmaf(hd[4 * j + 0], w[12 + j].x, a0);
            a1 = fmaf(hd[4 * j + 1], w[12 + j].y, a1);
            a2 = fmaf(hd[4 * j + 2], w[12 + j].z, a2);
            a3 = fmaf(hd[4 * j + 3], w[12 + j].w, a3);
        }
        const float val = ((a0 + a1) + (a2 + a3)) + bias;
        float* orow = qkvs + (size_t)(base + i) * 192;
        if (sec == 0) {
            orow[lane] = val;                              // q, f32
        } else if (sec == 1) {
            orow[128 + lane] = val;                        // skip, f32
        } else {
            __half* kvh = (__half*)(orow + 64);
            kvh[((sec - 2) << 6) + lane] = __float2half(val);
        }
    }
}

// ---------------------------------------------------------------------------
// CSR build: histogram -> 3-kernel parallel scan -> XCD-partitioned scatter
// erec record: 8B = {src:u32, attrs:half2}
// ---------------------------------------------------------------------------
__global__ __launch_bounds__(256) void k_hist(const int* __restrict__ ei,
                                              int* __restrict__ deg) {
    const int e = blockIdx.x * 256 + threadIdx.x;
    if (e >= NE) return;
    atomicAdd(&deg[ei[NE + e]], 1);
}

__global__ __launch_bounds__(256) void k_blocksum(const int* __restrict__ deg,
                                                  int* __restrict__ bsum) {
    __shared__ int sh[256];
    const int t = threadIdx.x;
    const int idx = blockIdx.x * 256 + t;
    sh[t] = (idx < NN) ? deg[idx] : 0;
    __syncthreads();
#pragma unroll
    for (int off = 128; off > 0; off >>= 1) {
        if (t < off) sh[t] += sh[t + off];
        __syncthreads();
    }
    if (t == 0) bsum[blockIdx.x] = sh[0];
}

__global__ __launch_bounds__(256) void k_scanb(const int* __restrict__ bsum,
                                               int* __restrict__ boff) {
    __shared__ int sh[256];
    const int t = threadIdx.x;
    const int v = (t < SCAN_BLOCKS) ? bsum[t] : 0;
    sh[t] = v;
    __syncthreads();
#pragma unroll
    for (int off = 1; off < 256; off <<= 1) {
        const int x = (t >= off) ? sh[t - off] : 0;
        __syncthreads();
        sh[t] += x;
        __syncthreads();
    }
    if (t < SCAN_BLOCKS) boff[t] = sh[t] - v;  // exclusive
}

__global__ __launch_bounds__(256) void k_writeptr(const int* __restrict__ deg,
                                                  const int* __restrict__ boff,
                                                  int* __restrict__ row_ptr,
                                                  int* __restrict__ cursor) {
    __shared__ int sh[256];
    const int t = threadIdx.x;
    const int idx = blockIdx.x * 256 + t;
    const int v = (idx < NN) ? deg[idx] : 0;
    sh[t] = v;
    __syncthreads();
#pragma unroll
    for (int off = 1; off < 256; off <<= 1) {
        const int x = (t >= off) ? sh[t - off] : 0;
        __syncthreads();
        sh[t] += x;
        __syncthreads();
    }
    if (idx < NN) {
        const int r = boff[blockIdx.x] + sh[t] - v;  // exclusive prefix
        row_ptr[idx] = r;
        cursor[idx] = r;
    }
    if (idx == 0) row_ptr[NN] = NE;
}

// XCD-ownership-partitioned scatter: 8 filter-replicas per 256-edge chunk.
__global__ __launch_bounds__(256) void k_csr(const int* __restrict__ ei,
                                             const float* __restrict__ eattr,
                                             const int* __restrict__ row_ptr,
                                             int* __restrict__ cursor,
                                             uint2* __restrict__ erec) {
    const int chunk = blockIdx.x >> 3;
    const unsigned myx = blockIdx.x & 7;
    const int e = chunk * 256 + threadIdx.x;     // NE = 3125*256 exact
    const int dst = ei[NE + e];
    const int rp = row_ptr[dst];
    const unsigned owner = (unsigned)rp / (NE / 8u);
    if (owner != myx) return;
    const int pos = atomicAdd(&cursor[dst], 1);
    const __half2 a = __floats2half2_rn(eattr[e * 2], eattr[e * 2 + 1]);
    erec[pos] = make_uint2((unsigned)ei[e], *(const unsigned*)&a);
}

// ---------------------------------------------------------------------------
// K2: fused conv, 16-lane edge groups. Wave = 1 destination, 4 groups of 16
// lanes each process one edge; lane p covers channels 4p..4p+3. Dot reduce =
// 4-step shfl_xor. Softmax state per group, merged by 2-step butterfly.
// ---------------------------------------------------------------------------
__global__ __launch_bounds__(256) void k_conv(const int* __restrict__ row_ptr,
                                              const uint2* __restrict__ erec,
                                              const float* __restrict__ We,
                                              const float* __restrict__ qkvs,
                                              float* __restrict__ hout) {
    const int t = threadIdx.x;
    const int lane = t & 63;
    const int g = lane >> 4;          // edge-group 0..3
    const int p = lane & 15;          // channel-quarter position
    const int wv = __builtin_amdgcn_readfirstlane(t) >> 6;
    const int d = blockIdx.x * 4 + wv;
    if (d >= NN) return;

    const float* qrow = qkvs + (size_t)d * 192;
    const float4 q4  = *(const float4*)(qrow + 4 * p);
    const float4 w0  = *(const float4*)(We + 4 * p);
    const float4 w1  = *(const float4*)(We + 64 + 4 * p);

    float pg0 = q4.x * w0.x + q4.y * w0.y + q4.z * w0.z + q4.w * w0.w;
    float pg1 = q4.x * w1.x + q4.y * w1.y + q4.z * w1.z + q4.w * w1.w;
#pragma unroll
    for (int mask = 1; mask <= 8; mask <<= 1) {
        pg0 += __shfl_xor(pg0, mask);
        pg1 += __shfl_xor(pg1, mask);
    }
    const float g0 = pg0, g1 = pg1;

    const int i0 = row_ptr[d], i1 = row_ptr[d + 1];
    const char* kvbase = (const char*)qkvs + 256 + ((size_t)p << 4);

    float m = -1e30f, l = 0.f, S1 = 0.f, S2 = 0.f;
    float4 acc = make_float4(0.f, 0.f, 0.f, 0.f);

#pragma unroll 2
    for (int i = i0 + g; i < i1; i += 4) {
        const uint2 r = erec[i];
        const __half2 ah = *(const __half2*)&r.y;
        const float a0 = __low2float(ah), a1 = __high2float(ah);
        const float4 kvl = *(const float4*)(kvbase + (size_t)r.x * 768);
        const __half2* hv = (const __half2*)&kvl;
        const float kf0 = __low2float(hv[0]), vf0 = __high2float(hv[0]);
        const float kf1 = __low2float(hv[1]), vf1 = __high2float(hv[1]);
        const float kf2 = __low2float(hv[2]), vf2 = __high2float(hv[2]);
        const float kf3 = __low2float(hv[3]), vf3 = __high2float(hv[3]);
        float dot = q4.x * kf0 + q4.y * kf1 + q4.z * kf2 + q4.w * kf3;
        dot += __shfl_xor(dot, 1);
        dot += __shfl_xor(dot, 2);
        dot += __shfl_xor(dot, 4);
        dot += __shfl_xor(dot, 8);
        const float P = (dot + g0 * a0 + g1 * a1) * 0.125f;
        const float mn = fmaxf(m, P);
        const float s = __expf(m - mn);
        const float e = __expf(P - mn);
        l = l * s + e;
        acc.x = acc.x * s + vf0 * e;
        acc.y = acc.y * s + vf1 * e;
        acc.z = acc.z * s + vf2 * e;
        acc.w = acc.w * s + vf3 * e;
        S1 = S1 * s + a0 * e;
        S2 = S2 * s + a1 * e;
        m = mn;
    }

#pragma unroll
    for (int mask = 16; mask <= 32; mask <<= 1) {
        const float mo  = __shfl_xor(m, mask);
        const float lo  = __shfl_xor(l, mask);
        const float axo = __shfl_xor(acc.x, mask);
        const float ayo = __shfl_xor(acc.y, mask);
        const float azo = __shfl_xor(acc.z, mask);
        const float awo = __shfl_xor(acc.w, mask);
        const float S1o = __shfl_xor(S1, mask);
        const float S2o = __shfl_xor(S2, mask);
        const float mn = fmaxf(m, mo);
        const float sA = __expf(m - mn);
        const float sB = __expf(mo - mn);
        l     = l * sA + lo * sB;
        acc.x = acc.x * sA + axo * sB;
        acc.y = acc.y * sA + ayo * sB;
        acc.z = acc.z * sA + azo * sB;
        acc.w = acc.w * sA + awo * sB;
        S1    = S1 * sA + S1o * sB;
        S2    = S2 * sA + S2o * sB;
        m = mn;
    }

    if (lane < 16) {
        const float inv = (l > 0.f) ? 1.f / l : 0.f;
        const float4 sk = *(const float4*)(qrow + 128 + 4 * p);
        float4 r;
        r.x = leaky((acc.x + S1 * w0.x + S2 * w1.x) * inv + sk.x);
        r.y = leaky((acc.y + S1 * w0.y + S2 * w1.y) * inv + sk.y);
        r.z = leaky((acc.z + S1 * w0.z + S2 * w1.z) * inv + sk.z);
        r.w = leaky((acc.w + S1 * w0.w + S2 * w1.w) * inv + sk.w);
        *(float4*)(hout + (size_t)d * C + 4 * p) = r;
    }
}

extern "C" void kernel_launch(void* const* d_in, const int* in_sizes, int n_in,
                              void* d_out, int out_size, void* d_ws, size_t ws_size,
                              hipStream_t stream) {
    const float* x     = (const float*)d_in[0];
    const int*   ei    = (const int*)d_in[1];
    const float* eattr = (const float*)d_in[2];
    const float* Wf    = (const float*)d_in[3];
    const float* bf    = (const float*)d_in[4];
    const float* Wq    = (const float*)d_in[5];
    const float* bq    = (const float*)d_in[6];
    const float* Wk    = (const float*)d_in[7];
    const float* bk    = (const float*)d_in[8];
    const float* Wv    = (const float*)d_in[9];
    const float* bv    = (const float*)d_in[10];
    const float* We    = (const float*)d_in[11];
    const float* Ws    = (const float*)d_in[12];
    const float* bs    = (const float*)d_in[13];
    float* out = (float*)d_out;

    // workspace layout
    char* p = (char*)d_ws;
    float*  h       = (float*)p;  p += (size_t)NN * C * 4;        // 12.8 MB
    float*  qkvs    = (float*)p;  p += (size_t)NN * 192 * 4;      // 38.4 MB
    float*  Wt      = (float*)p;  p += (size_t)4 * 64 * 64 * 4;   // 64 KB
    int*    deg     = (int*)p;    p += (size_t)NN * 4;
    int*    row_ptr = (int*)p;    p += (size_t)(NN + 1) * 4;
    int*    cursor  = (int*)p;    p += (size_t)NN * 4;
    int*    bsum    = (int*)p;    p += (size_t)SCAN_BLOCKS * 4;
    int*    boff    = (int*)p;    p += (size_t)SCAN_BLOCKS * 4;
    uint2*  erec    = (uint2*)p;  p += (size_t)NE * 8;            // 6.4 MB

    // One-time per call: weight transpose + CSR build
    k_tw<<<64, 256, 0, stream>>>(Wq, Wk, Wv, Ws, Wt);
    hipMemsetAsync(deg, 0, (size_t)NN * 4, stream);
    k_hist<<<CSR_CHUNKS, 256, 0, stream>>>(ei, deg);
    k_blocksum<<<SCAN_BLOCKS, 256, 0, stream>>>(deg, bsum);
    k_scanb<<<1, 256, 0, stream>>>(bsum, boff);
    k_writeptr<<<SCAN_BLOCKS, 256, 0, stream>>>(deg, boff, row_ptr, cursor);
    k_csr<<<CSR_CHUNKS * 8, 256, 0, stream>>>(ei, eattr, row_ptr, cursor, erec);

    const int feat_grid = (NN + 63) / 64;                   // 782
    const int qkvs_grid = (NN + QKVS_NPB - 1) / QKVS_NPB;   // 1563

    k_feat<<<feat_grid, 256, 0, stream>>>(x, Wf, bf, h);

    for (int layer = 0; layer < 3; ++layer) {
        k_qkvs<<<qkvs_grid, 256, 0, stream>>>(h, Wt, bq, bk, bv, bs, qkvs);
        float* hout = (layer == 2) ? out : h;
        k_conv<<<(NN + 3) / 4, 256, 0, stream>>>(row_ptr, erec, We, qkvs, hout);
    }
}

// Round 8
// 426.387 us; speedup vs baseline: 2.5924x; 1.1319x over previous
//
#include <hip/hip_runtime.h>
#include <hip/hip_fp16.h>

#define NN 50000
#define NE 800000
#define FIN 256
#define C 64
#define NEG_SLOPE 0.01f
#define SCAN_BLOCKS ((NN + 255) / 256)   // 196
#define NBUCK 196                        // bucket = dst >> 8 (dst < 50176)
#define BCAP 8192                        // per-bucket capacity (mean 4082, 64 sigma)
#define EB_CHUNK 2048
#define EB_BLOCKS ((NE + EB_CHUNK - 1) / EB_CHUNK)   // 391

typedef float f32x16 __attribute__((ext_vector_type(16)));

__device__ __forceinline__ float leaky(float v) { return v > 0.f ? v : NEG_SLOPE * v; }

// ---------------------------------------------------------------------------
// Weight transpose: Wt[m][c][k] = W_m[k][c], m in {q,k,v,skip}. 16384 elems.
// ---------------------------------------------------------------------------
__global__ __launch_bounds__(256) void k_tw(const float* __restrict__ Wq,
                                            const float* __restrict__ Wk,
                                            const float* __restrict__ Wv,
                                            const float* __restrict__ Ws,
                                            float* __restrict__ Wt) {
    const int idx = blockIdx.x * 256 + threadIdx.x;
    if (idx >= 4 * 64 * 64) return;
    const int m = idx >> 12, r = idx & 4095, c = r >> 6, k = r & 63;
    const float* W = (m == 0) ? Wq : (m == 1) ? Wk : (m == 2) ? Wv : Ws;
    Wt[idx] = W[k * 64 + c];
}

// ---------------------------------------------------------------------------
// K0: h = leaky_relu(x @ Wf + bf).
// lane = node (per-lane-DISTINCT LDS reads: 1 ds_read_b128 -> 64 FMAs),
// wave = col-quarter, weights broadcast via s_load_dwordx16 (L2/K$-hot).
// ---------------------------------------------------------------------------
__global__ __launch_bounds__(256) void k_feat(const float* __restrict__ x,
                                              const float* __restrict__ Wf,
                                              const float* __restrict__ bf,
                                              float* __restrict__ h) {
    __shared__ float4 Sx[64][33];   // 33.8 KB; +1 pad
    const int t = threadIdx.x;
    const int lane = t & 63;
    const int q = __builtin_amdgcn_readfirstlane(t) >> 6;   // col-quarter
    const int base = blockIdx.x * 64;

    const float4* x4 = (const float4*)x;
    float4 acc[4];
#pragma unroll
    for (int cp = 0; cp < 4; ++cp) acc[cp] = make_float4(0.f, 0.f, 0.f, 0.f);

#define FRAG(wreg, xs)                                                      \
    acc[0].x = fmaf(xs, wreg[0],  acc[0].x);                                \
    acc[0].y = fmaf(xs, wreg[1],  acc[0].y);                                \
    acc[0].z = fmaf(xs, wreg[2],  acc[0].z);                                \
    acc[0].w = fmaf(xs, wreg[3],  acc[0].w);                                \
    acc[1].x = fmaf(xs, wreg[4],  acc[1].x);                                \
    acc[1].y = fmaf(xs, wreg[5],  acc[1].y);                                \
    acc[1].z = fmaf(xs, wreg[6],  acc[1].z);                                \
    acc[1].w = fmaf(xs, wreg[7],  acc[1].w);                                \
    acc[2].x = fmaf(xs, wreg[8],  acc[2].x);                                \
    acc[2].y = fmaf(xs, wreg[9],  acc[2].y);                                \
    acc[2].z = fmaf(xs, wreg[10], acc[2].z);                                \
    acc[2].w = fmaf(xs, wreg[11], acc[2].w);                                \
    acc[3].x = fmaf(xs, wreg[12], acc[3].x);                                \
    acc[3].y = fmaf(xs, wreg[13], acc[3].y);                                \
    acc[3].z = fmaf(xs, wreg[14], acc[3].z);                                \
    acc[3].w = fmaf(xs, wreg[15], acc[3].w);

    for (int ph = 0; ph < 2; ++ph) {
#pragma unroll
        for (int i = 0; i < 8; ++i) {
            const int idx = t + i * 256;
            const int row = idx >> 5, c = idx & 31;
            int nn = base + row; if (nn >= NN) nn = NN - 1;
            Sx[row][c] = x4[(size_t)nn * 64 + ph * 32 + c];
        }
        __syncthreads();

        const float* wbase = Wf + (size_t)(ph * 128) * 64 + q * 16;
#pragma unroll
        for (int j = 0; j < 32; ++j) {
            const float4 xv = Sx[lane][j];
            const float* wrow = wbase + (size_t)j * 256;
            f32x16 w0_, w1_, w2_, w3_;
            asm volatile("s_load_dwordx16 %0, %4, 0x0\n\t"
                         "s_load_dwordx16 %1, %4, 0x100\n\t"
                         "s_load_dwordx16 %2, %4, 0x200\n\t"
                         "s_load_dwordx16 %3, %4, 0x300\n\t"
                         "s_waitcnt lgkmcnt(0)"
                         : "=&s"(w0_), "=&s"(w1_), "=&s"(w2_), "=&s"(w3_)
                         : "s"(wrow));
            FRAG(w0_, xv.x)
            FRAG(w1_, xv.y)
            FRAG(w2_, xv.z)
            FRAG(w3_, xv.w)
        }
        __syncthreads();
    }
#undef FRAG

    float4* O = (float4*)Sx;
    const float4* bf4 = (const float4*)bf;
#pragma unroll
    for (int cp = 0; cp < 4; ++cp) {
        const float4 b = bf4[q * 4 + cp];
        float4 r;
        r.x = leaky(acc[cp].x + b.x); r.y = leaky(acc[cp].y + b.y);
        r.z = leaky(acc[cp].z + b.z); r.w = leaky(acc[cp].w + b.w);
        O[lane * 17 + q * 4 + cp] = r;
    }
    __syncthreads();
#pragma unroll
    for (int i = 0; i < 4; ++i) {
        const int idx = t + i * 256;
        const int row = idx >> 4, c = idx & 15;
        const int nn = base + row;
        if (nn < NN) ((float4*)h)[(size_t)nn * 16 + c] = O[row * 17 + c];
    }
}

// ---------------------------------------------------------------------------
// K1: qkvs row (192 floats = 768B): [q f32(64) | k/v fp16 interleaved(128h) |
// skip f32(64)].  Transposed mapping, SGPR h-row broadcast (h is L2-hot),
// coalesced stores.
// ---------------------------------------------------------------------------
#define QKVS_NPB 32   // nodes per block

__global__ __launch_bounds__(256) void k_qkvs(const float* __restrict__ h,
                                              const float* __restrict__ Wt,
                                              const float* __restrict__ bq,
                                              const float* __restrict__ bk,
                                              const float* __restrict__ bv,
                                              const float* __restrict__ bs,
                                              float* __restrict__ qkvs) {
    const int t = threadIdx.x;
    const int lane = t & 63;
    const int sec = __builtin_amdgcn_readfirstlane(t) >> 6;
    const int base = blockIdx.x * QKVS_NPB;

    int m, cidx;
    float bias;
    if (sec == 0)      { m = 0; cidx = lane; bias = bq[lane]; }
    else if (sec == 1) { m = 3; cidx = lane; bias = bs[lane]; }
    else {
        cidx = ((sec - 2) << 5) + (lane >> 1);   // k/v column
        m = 1 + (lane & 1);                      // even lane -> Wk, odd -> Wv
        bias = (lane & 1) ? bv[cidx] : bk[cidx];
    }

    const float4* wb = (const float4*)(Wt + ((size_t)m << 12) + ((size_t)cidx << 6));
    float4 w[16];
#pragma unroll
    for (int j = 0; j < 16; ++j) w[j] = wb[j];

    const int nmax = (base + QKVS_NPB <= NN) ? QKVS_NPB : (NN - base);
    for (int i = 0; i < nmax; ++i) {
        const float* hrow = h + (size_t)(base + i) * 64;   // wave-uniform
        f32x16 ha, hb, hc, hd;
        asm volatile("s_load_dwordx16 %0, %4, 0x0\n\t"
                     "s_load_dwordx16 %1, %4, 0x40\n\t"
                     "s_load_dwordx16 %2, %4, 0x80\n\t"
                     "s_load_dwordx16 %3, %4, 0xc0\n\t"
                     "s_waitcnt lgkmcnt(0)"
                     : "=&s"(ha), "=&s"(hb), "=&s"(hc), "=&s"(hd)
                     : "s"(hrow));
        float a0 = 0.f, a1 = 0.f, a2 = 0.f, a3 = 0.f;
#pragma unroll
        for (int j = 0; j < 4; ++j) {
            a0 = fmaf(ha[4 * j + 0], w[j].x, a0);
            a1 = fmaf(ha[4 * j + 1], w[j].y, a1);
            a2 = fmaf(ha[4 * j + 2], w[j].z, a2);
            a3 = fmaf(ha[4 * j + 3], w[j].w, a3);
        }
#pragma unroll
        for (int j = 0; j < 4; ++j) {
            a0 = fmaf(hb[4 * j + 0], w[4 + j].x, a0);
            a1 = fmaf(hb[4 * j + 1], w[4 + j].y, a1);
            a2 = fmaf(hb[4 * j + 2], w[4 + j].z, a2);
            a3 = fmaf(hb[4 * j + 3], w[4 + j].w, a3);
        }
#pragma unroll
        for (int j = 0; j < 4; ++j) {
            a0 = fmaf(hc[4 * j + 0], w[8 + j].x, a0);
            a1 = fmaf(hc[4 * j + 1], w[8 + j].y, a1);
            a2 = fmaf(hc[4 * j + 2], w[8 + j].z, a2);
            a3 = fmaf(hc[4 * j + 3], w[8 + j].w, a3);
        }
#pragma unroll
        for (int j = 0; j < 4; ++j) {
            a0 = fmaf(hd[4 * j + 0], w[12 + j].x, a0);
            a1 = fmaf(hd[4 * j + 1], w[12 + j].y, a1);
            a2 = fmaf(hd[4 * j + 2], w[12 + j].z, a2);
            a3 = fmaf(hd[4 * j + 3], w[12 + j].w, a3);
        }
        const float val = ((a0 + a1) + (a2 + a3)) + bias;
        float* orow = qkvs + (size_t)(base + i) * 192;
        if (sec == 0) {
            orow[lane] = val;                              // q, f32
        } else if (sec == 1) {
            orow[128 + lane] = val;                        // skip, f32
        } else {
            __half* kvh = (__half*)(orow + 64);
            kvh[((sec - 2) << 6) + lane] = __float2half(val);
        }
    }
}

// ---------------------------------------------------------------------------
// Atomic-free CSR build (bucketed counting sort).
// bucket = dst >> 8 (196 buckets, ~4082 edges each). Only LDS atomics +
// 77K aggregated global atomics (vs 1.6M per-edge device atomics before,
// each a memory-side RMW ~ the measured 50us k_csr + hidden k_hist cost).
// Packed record: {x = dst<<16 | src, y = half2(attr)} (both ids < 65536).
// ---------------------------------------------------------------------------
__global__ __launch_bounds__(256) void k_bucket(const int* __restrict__ ei,
                                                const float* __restrict__ eattr,
                                                int* __restrict__ gcur,
                                                uint2* __restrict__ ebuck) {
    __shared__ int hist[NBUCK], lbase[NBUCK], lcur[NBUCK];
    const int t = threadIdx.x;
    const int base = blockIdx.x * EB_CHUNK;
    if (t < NBUCK) { hist[t] = 0; lcur[t] = 0; }
    __syncthreads();

    int dcache[8];
#pragma unroll
    for (int i = 0; i < 8; ++i) {
        const int e = base + i * 256 + t;
        int d = -1;
        if (e < NE) {
            d = ei[NE + e];
            atomicAdd(&hist[d >> 8], 1);
        }
        dcache[i] = d;
    }
    __syncthreads();
    if (t < NBUCK && hist[t] > 0)
        lbase[t] = atomicAdd(&gcur[t], hist[t]);
    __syncthreads();

#pragma unroll
    for (int i = 0; i < 8; ++i) {
        const int e = base + i * 256 + t;
        const int d = dcache[i];
        if (d >= 0) {
            const int b = d >> 8;
            const int rank = atomicAdd(&lcur[b], 1);
            const __half2 a = __floats2half2_rn(eattr[e * 2], eattr[e * 2 + 1]);
            const unsigned src = (unsigned)ei[e];
            ebuck[(size_t)b * BCAP + lbase[b] + rank] =
                make_uint2(((unsigned)d << 16) | src, *(const unsigned*)&a);
        }
    }
}

// one block per bucket: per-dst counts via LDS -> deg (replaces k_hist)
__global__ __launch_bounds__(256) void k_fin_deg(const int* __restrict__ gcur,
                                                 const uint2* __restrict__ ebuck,
                                                 int* __restrict__ deg) {
    __shared__ int dcnt[256];
    const int t = threadIdx.x;
    const int b = blockIdx.x;
    dcnt[t] = 0;
    __syncthreads();
    const int n = gcur[b];
    for (int i = t; i < n; i += 256) {
        const unsigned x = ebuck[(size_t)b * BCAP + i].x;
        atomicAdd(&dcnt[(x >> 16) & 255], 1);
    }
    __syncthreads();
    const int idx = b * 256 + t;
    if (idx < NN) deg[idx] = dcnt[t];
}

__global__ __launch_bounds__(256) void k_blocksum(const int* __restrict__ deg,
                                                  int* __restrict__ bsum) {
    __shared__ int sh[256];
    const int t = threadIdx.x;
    const int idx = blockIdx.x * 256 + t;
    sh[t] = (idx < NN) ? deg[idx] : 0;
    __syncthreads();
#pragma unroll
    for (int off = 128; off > 0; off >>= 1) {
        if (t < off) sh[t] += sh[t + off];
        __syncthreads();
    }
    if (t == 0) bsum[blockIdx.x] = sh[0];
}

__global__ __launch_bounds__(256) void k_scanb(const int* __restrict__ bsum,
                                               int* __restrict__ boff) {
    __shared__ int sh[256];
    const int t = threadIdx.x;
    const int v = (t < SCAN_BLOCKS) ? bsum[t] : 0;
    sh[t] = v;
    __syncthreads();
#pragma unroll
    for (int off = 1; off < 256; off <<= 1) {
        const int x = (t >= off) ? sh[t - off] : 0;
        __syncthreads();
        sh[t] += x;
        __syncthreads();
    }
    if (t < SCAN_BLOCKS) boff[t] = sh[t] - v;  // exclusive
}

__global__ __launch_bounds__(256) void k_writeptr(const int* __restrict__ deg,
                                                  const int* __restrict__ boff,
                                                  int* __restrict__ row_ptr) {
    __shared__ int sh[256];
    const int t = threadIdx.x;
    const int idx = blockIdx.x * 256 + t;
    const int v = (idx < NN) ? deg[idx] : 0;
    sh[t] = v;
    __syncthreads();
#pragma unroll
    for (int off = 1; off < 256; off <<= 1) {
        const int x = (t >= off) ? sh[t - off] : 0;
        __syncthreads();
        sh[t] += x;
        __syncthreads();
    }
    if (idx < NN) row_ptr[idx] = boff[blockIdx.x] + sh[t] - v;  // exclusive
    if (idx == 0) row_ptr[NN] = NE;
}

// one block per bucket: final scatter with LDS cursors seeded from row_ptr.
// Each bucket's erec output region is contiguous and written by one block
// (one XCD) -> clean L2-local full-line writebacks, zero global atomics.
__global__ __launch_bounds__(256) void k_fin_scat(const int* __restrict__ gcur,
                                                  const uint2* __restrict__ ebuck,
                                                  const int* __restrict__ row_ptr,
                                                  uint2* __restrict__ erec) {
    __shared__ int pcur[256];
    const int t = threadIdx.x;
    const int b = blockIdx.x;
    const int idx = b * 256 + t;
    pcur[t] = (idx < NN) ? row_ptr[idx] : 0;
    __syncthreads();
    const int n = gcur[b];
    for (int i = t; i < n; i += 256) {
        const uint2 rec = ebuck[(size_t)b * BCAP + i];
        const int d = (rec.x >> 16) & 255;
        const int pos = atomicAdd(&pcur[d], 1);
        erec[pos] = make_uint2(rec.x & 0xFFFFu, rec.y);
    }
}

// ---------------------------------------------------------------------------
// K2: fused conv, 16-lane edge groups, 2-edge unroll per group (8 edges per
// wave-iteration) for memory-level parallelism. Dot reduce = 4-step shfl_xor.
// Softmax state per group, merged by 2-step butterfly.
// ---------------------------------------------------------------------------
__global__ __launch_bounds__(256) void k_conv(const int* __restrict__ row_ptr,
                                              const uint2* __restrict__ erec,
                                              const float* __restrict__ We,
                                              const float* __restrict__ qkvs,
                                              float* __restrict__ hout) {
    const int t = threadIdx.x;
    const int lane = t & 63;
    const int g = lane >> 4;          // edge-group 0..3
    const int p = lane & 15;          // channel-quarter position
    const int wv = __builtin_amdgcn_readfirstlane(t) >> 6;
    const int d = blockIdx.x * 4 + wv;
    if (d >= NN) return;

    const float* qrow = qkvs + (size_t)d * 192;
    const float4 q4  = *(const float4*)(qrow + 4 * p);
    const float4 w0  = *(const float4*)(We + 4 * p);
    const float4 w1  = *(const float4*)(We + 64 + 4 * p);

    float pg0 = q4.x * w0.x + q4.y * w0.y + q4.z * w0.z + q4.w * w0.w;
    float pg1 = q4.x * w1.x + q4.y * w1.y + q4.z * w1.z + q4.w * w1.w;
#pragma unroll
    for (int mask = 1; mask <= 8; mask <<= 1) {
        pg0 += __shfl_xor(pg0, mask);
        pg1 += __shfl_xor(pg1, mask);
    }
    const float g0 = pg0, g1 = pg1;

    const int i0 = row_ptr[d], i1 = row_ptr[d + 1];
    const char* kvbase = (const char*)qkvs + 256 + ((size_t)p << 4);

    float m = -1e30f, l = 0.f, S1 = 0.f, S2 = 0.f;
    float4 acc = make_float4(0.f, 0.f, 0.f, 0.f);

    int i = i0 + g;
    for (; i + 4 < i1; i += 8) {       // two edges per group-iteration
        const uint2 ra = erec[i];
        const uint2 rb = erec[i + 4];
        const __half2 aha = *(const __half2*)&ra.y;
        const __half2 ahb = *(const __half2*)&rb.y;
        const float a0a = __low2float(aha), a1a = __high2float(aha);
        const float a0b = __low2float(ahb), a1b = __high2float(ahb);
        const float4 kva = *(const float4*)(kvbase + (size_t)ra.x * 768);
        const float4 kvb = *(const float4*)(kvbase + (size_t)rb.x * 768);
        const __half2* ha = (const __half2*)&kva;
        const __half2* hb = (const __half2*)&kvb;
        const float ka0 = __low2float(ha[0]), va0 = __high2float(ha[0]);
        const float ka1 = __low2float(ha[1]), va1 = __high2float(ha[1]);
        const float ka2 = __low2float(ha[2]), va2 = __high2float(ha[2]);
        const float ka3 = __low2float(ha[3]), va3 = __high2float(ha[3]);
        const float kb0 = __low2float(hb[0]), vb0 = __high2float(hb[0]);
        const float kb1 = __low2float(hb[1]), vb1 = __high2float(hb[1]);
        const float kb2 = __low2float(hb[2]), vb2 = __high2float(hb[2]);
        const float kb3 = __low2float(hb[3]), vb3 = __high2float(hb[3]);
        float da = q4.x * ka0 + q4.y * ka1 + q4.z * ka2 + q4.w * ka3;
        float db = q4.x * kb0 + q4.y * kb1 + q4.z * kb2 + q4.w * kb3;
        da += __shfl_xor(da, 1);  db += __shfl_xor(db, 1);
        da += __shfl_xor(da, 2);  db += __shfl_xor(db, 2);
        da += __shfl_xor(da, 4);  db += __shfl_xor(db, 4);
        da += __shfl_xor(da, 8);  db += __shfl_xor(db, 8);
        const float Pa = (da + g0 * a0a + g1 * a1a) * 0.125f;
        const float Pb = (db + g0 * a0b + g1 * a1b) * 0.125f;
        const float mn = fmaxf(m, fmaxf(Pa, Pb));
        const float s  = __expf(m - mn);
        const float ea = __expf(Pa - mn);
        const float eb = __expf(Pb - mn);
        l = l * s + ea + eb;
        acc.x = acc.x * s + va0 * ea + vb0 * eb;
        acc.y = acc.y * s + va1 * ea + vb1 * eb;
        acc.z = acc.z * s + va2 * ea + vb2 * eb;
        acc.w = acc.w * s + va3 * ea + vb3 * eb;
        S1 = S1 * s + a0a * ea + a0b * eb;
        S2 = S2 * s + a1a * ea + a1b * eb;
        m = mn;
    }
    for (; i < i1; i += 4) {
        const uint2 r = erec[i];
        const __half2 ah = *(const __half2*)&r.y;
        const float a0 = __low2float(ah), a1 = __high2float(ah);
        const float4 kvl = *(const float4*)(kvbase + (size_t)r.x * 768);
        const __half2* hv = (const __half2*)&kvl;
        const float kf0 = __low2float(hv[0]), vf0 = __high2float(hv[0]);
        const float kf1 = __low2float(hv[1]), vf1 = __high2float(hv[1]);
        const float kf2 = __low2float(hv[2]), vf2 = __high2float(hv[2]);
        const float kf3 = __low2float(hv[3]), vf3 = __high2float(hv[3]);
        float dot = q4.x * kf0 + q4.y * kf1 + q4.z * kf2 + q4.w * kf3;
        dot += __shfl_xor(dot, 1);
        dot += __shfl_xor(dot, 2);
        dot += __shfl_xor(dot, 4);
        dot += __shfl_xor(dot, 8);
        const float P = (dot + g0 * a0 + g1 * a1) * 0.125f;
        const float mn = fmaxf(m, P);
        const float s = __expf(m - mn);
        const float e = __expf(P - mn);
        l = l * s + e;
        acc.x = acc.x * s + vf0 * e;
        acc.y = acc.y * s + vf1 * e;
        acc.z = acc.z * s + vf2 * e;
        acc.w = acc.w * s + vf3 * e;
        S1 = S1 * s + a0 * e;
        S2 = S2 * s + a1 * e;
        m = mn;
    }

#pragma unroll
    for (int mask = 16; mask <= 32; mask <<= 1) {
        const float mo  = __shfl_xor(m, mask);
        const float lo  = __shfl_xor(l, mask);
        const float axo = __shfl_xor(acc.x, mask);
        const float ayo = __shfl_xor(acc.y, mask);
        const float azo = __shfl_xor(acc.z, mask);
        const float awo = __shfl_xor(acc.w, mask);
        const float S1o = __shfl_xor(S1, mask);
        const float S2o = __shfl_xor(S2, mask);
        const float mn = fmaxf(m, mo);
        const float sA = __expf(m - mn);
        const float sB = __expf(mo - mn);
        l     = l * sA + lo * sB;
        acc.x = acc.x * sA + axo * sB;
        acc.y = acc.y * sA + ayo * sB;
        acc.z = acc.z * sA + azo * sB;
        acc.w = acc.w * sA + awo * sB;
        S1    = S1 * sA + S1o * sB;
        S2    = S2 * sA + S2o * sB;
        m = mn;
    }

    if (lane < 16) {
        const float inv = (l > 0.f) ? 1.f / l : 0.f;
        const float4 sk = *(const float4*)(qrow + 128 + 4 * p);
        float4 r;
        r.x = leaky((acc.x + S1 * w0.x + S2 * w1.x) * inv + sk.x);
        r.y = leaky((acc.y + S1 * w0.y + S2 * w1.y) * inv + sk.y);
        r.z = leaky((acc.z + S1 * w0.z + S2 * w1.z) * inv + sk.z);
        r.w = leaky((acc.w + S1 * w0.w + S2 * w1.w) * inv + sk.w);
        *(float4*)(hout + (size_t)d * C + 4 * p) = r;
    }
}

extern "C" void kernel_launch(void* const* d_in, const int* in_sizes, int n_in,
                              void* d_out, int out_size, void* d_ws, size_t ws_size,
                              hipStream_t stream) {
    const float* x     = (const float*)d_in[0];
    const int*   ei    = (const int*)d_in[1];
    const float* eattr = (const float*)d_in[2];
    const float* Wf    = (const float*)d_in[3];
    const float* bf    = (const float*)d_in[4];
    const float* Wq    = (const float*)d_in[5];
    const float* bq    = (const float*)d_in[6];
    const float* Wk    = (const float*)d_in[7];
    const float* bk    = (const float*)d_in[8];
    const float* Wv    = (const float*)d_in[9];
    const float* bv    = (const float*)d_in[10];
    const float* We    = (const float*)d_in[11];
    const float* Ws    = (const float*)d_in[12];
    const float* bs    = (const float*)d_in[13];
    float* out = (float*)d_out;

    // workspace layout
    char* p = (char*)d_ws;
    float*  h       = (float*)p;  p += (size_t)NN * C * 4;        // 12.8 MB
    float*  qkvs    = (float*)p;  p += (size_t)NN * 192 * 4;      // 38.4 MB
    float*  Wt      = (float*)p;  p += (size_t)4 * 64 * 64 * 4;   // 64 KB
    int*    deg     = (int*)p;    p += (size_t)NN * 4;
    int*    row_ptr = (int*)p;    p += (size_t)(NN + 1) * 4;
    int*    bsum    = (int*)p;    p += (size_t)SCAN_BLOCKS * 4;
    int*    boff    = (int*)p;    p += (size_t)SCAN_BLOCKS * 4;
    int*    gcur    = (int*)p;    p += (size_t)NBUCK * 4;
    uint2*  erec    = (uint2*)p;  p += (size_t)NE * 8;            // 6.4 MB
    uint2*  ebuck   = (uint2*)p;  p += (size_t)NBUCK * BCAP * 8;  // 12.85 MB

    // One-time per call: weight transpose + atomic-free CSR build
    k_tw<<<64, 256, 0, stream>>>(Wq, Wk, Wv, Ws, Wt);
    hipMemsetAsync(gcur, 0, (size_t)NBUCK * 4, stream);
    k_bucket<<<EB_BLOCKS, 256, 0, stream>>>(ei, eattr, gcur, ebuck);
    k_fin_deg<<<NBUCK, 256, 0, stream>>>(gcur, ebuck, deg);
    k_blocksum<<<SCAN_BLOCKS, 256, 0, stream>>>(deg, bsum);
    k_scanb<<<1, 256, 0, stream>>>(bsum, boff);
    k_writeptr<<<SCAN_BLOCKS, 256, 0, stream>>>(deg, boff, row_ptr);
    k_fin_scat<<<NBUCK, 256, 0, stream>>>(gcur, ebuck, row_ptr, erec);

    const int feat_grid = (NN + 63) / 64;                   // 782
    const int qkvs_grid = (NN + QKVS_NPB - 1) / QKVS_NPB;   // 1563

    k_feat<<<feat_grid, 256, 0, stream>>>(x, Wf, bf, h);

    for (int layer = 0; layer < 3; ++layer) {
        k_qkvs<<<qkvs_grid, 256, 0, stream>>>(h, Wt, bq, bk, bv, bs, qkvs);
        float* hout = (layer == 2) ? out : h;
        k_conv<<<(NN + 3) / 4, 256, 0, stream>>>(row_ptr, erec, We, qkvs, hout);
    }
}